// Round 10
// baseline (821.332 us; speedup 1.0000x reference)
//
#include <hip/hip_runtime.h>
#include <hip/hip_bf16.h>

#define NB 256          // edge-pass blocks
#define MAXBKT 512      // supports n <= 131072
#define CSH 12          // src chunk shift: 4096 rows = 1MB bf16 per chunk
#define DCAP 48         // per-node sort capacity

typedef __attribute__((ext_vector_type(8))) unsigned short ushort8;
typedef __attribute__((ext_vector_type(8))) short bf16x8;
typedef __attribute__((ext_vector_type(4))) float f32x4;

__device__ __forceinline__ unsigned short f2bf(float f) {
    unsigned u = __float_as_uint(f);
    unsigned r = (u + 0x7FFF + ((u >> 16) & 1)) >> 16;   // RNE
    return (unsigned short)r;
}

// ---- pass 1: per-(dstbkt, block) histogram of dst>>8 (zero global atomics) ----
__global__ __launch_bounds__(256) void k_hist1(const int* __restrict__ col, int E, int e2,
                                               int per, int* __restrict__ cnt, int nbkt) {
    __shared__ int h[MAXBKT];
    int t = threadIdx.x;
    for (int i = t; i < nbkt; i += 256) h[i] = 0;
    __syncthreads();
    int s = blockIdx.x * per, e = min(s + per, e2);
    for (int i = s + t; i < e; i += 256) {
        int dst = (i < E) ? col[i] : i - E;
        atomicAdd(&h[dst >> 8], 1);
    }
    __syncthreads();
    for (int i = t; i < nbkt; i += 256) cnt[i * NB + blockIdx.x] = h[i];
}

// ---- hierarchical exclusive scan ----
#define SCAN_T 256
#define SCAN_E 1024

__global__ void k_scan_a(const int* __restrict__ cnt, int n,
                         int* __restrict__ outp, int* __restrict__ bsum) {
    __shared__ int s[SCAN_T];
    int t = threadIdx.x, b = blockIdx.x;
    int base = b * SCAN_E + t * 4;
    int c0 = (base + 0 < n) ? cnt[base + 0] : 0;
    int c1 = (base + 1 < n) ? cnt[base + 1] : 0;
    int c2 = (base + 2 < n) ? cnt[base + 2] : 0;
    int c3 = (base + 3 < n) ? cnt[base + 3] : 0;
    int tsum = c0 + c1 + c2 + c3;
    s[t] = tsum; __syncthreads();
    for (int off = 1; off < SCAN_T; off <<= 1) {
        int v = (t >= off) ? s[t - off] : 0;
        __syncthreads();
        s[t] += v;
        __syncthreads();
    }
    int excl = s[t] - tsum;
    if (base + 0 < n) outp[base + 0] = excl;
    if (base + 1 < n) outp[base + 1] = excl + c0;
    if (base + 2 < n) outp[base + 2] = excl + c0 + c1;
    if (base + 3 < n) outp[base + 3] = excl + c0 + c1 + c2;
    if (t == 0) bsum[b] = s[SCAN_T - 1];
}

__global__ void k_scan_b(int* __restrict__ bsum, int nb) {
    __shared__ int s[128];
    int t = threadIdx.x;
    int v = (t < nb) ? bsum[t] : 0;
    s[t] = v; __syncthreads();
    for (int off = 1; off < 128; off <<= 1) {
        int u = (t >= off) ? s[t - off] : 0;
        __syncthreads();
        s[t] += u;
        __syncthreads();
    }
    if (t < nb) bsum[t] = s[t] - v;   // exclusive
}

__global__ void k_scan_c(int* __restrict__ outp, const int* __restrict__ bsum,
                         int n, int total) {
    int i = blockIdx.x * blockDim.x + threadIdx.x;
    if (i < n) outp[i] += bsum[i / SCAN_E];
    if (i == 0) outp[n] = total;
}

// ---- pass 3: scatter edges to exact dst-bucket-major slots (zero global atomics) ----
__global__ __launch_bounds__(256) void k_scatter1(const int* __restrict__ row,
                                                  const int* __restrict__ col,
                                                  const float* __restrict__ ew,
                                                  int E, int e2, int per,
                                                  const int* __restrict__ S,
                                                  uint2* __restrict__ csrR, int nbkt) {
    __shared__ int cur[MAXBKT];
    int t = threadIdx.x;
    for (int i = t; i < nbkt; i += 256) cur[i] = S[i * NB + blockIdx.x];
    __syncthreads();
    int s = blockIdx.x * per, e = min(s + per, e2);
    for (int i = s + t; i < e; i += 256) {
        int src, dst; float w;
        if (i < E) { src = row[i]; dst = col[i]; w = ew[i]; }
        else       { src = dst = i - E; w = 1.0f; }
        int slot = atomicAdd(&cur[dst >> 8], 1);
        csrR[slot] = make_uint2(((unsigned)src << 8) | (unsigned)(dst & 255),
                                __float_as_uint(w));
    }
}

// ---- pass 4: per-bucket regroup by dst; emits dinv, rowptr, final CSR ----
__global__ __launch_bounds__(256) void k_build(const uint2* __restrict__ csrR,
                                               const int* __restrict__ S,
                                               int n, int e2,
                                               float2* __restrict__ csrF,
                                               float* __restrict__ dinv,
                                               int* __restrict__ rowptr, int nbkt) {
    __shared__ int   cnt[256];
    __shared__ float wsm[256];
    __shared__ int   off[256];
    __shared__ float dvs[256];
    __shared__ int   curs[256];
    int b = blockIdx.x, t = threadIdx.x;
    cnt[t] = 0; wsm[t] = 0.f;
    __syncthreads();
    int base = S[b * NB], end = S[(b + 1) * NB];   // S[nbkt*NB] == e2
    for (int i = base + t; i < end; i += 256) {
        uint2 r = csrR[i];
        int d = r.x & 255;
        atomicAdd(&cnt[d], 1);
        atomicAdd(&wsm[d], __uint_as_float(r.y));
    }
    __syncthreads();
    int   myc = cnt[t];
    float w   = wsm[t];
    float dv  = (w > 0.f) ? rsqrtf(w) : 0.f;
    dvs[t] = dv;
    off[t] = myc;
    __syncthreads();
    for (int o = 1; o < 256; o <<= 1) {
        int v = (t >= o) ? off[t - o] : 0;
        __syncthreads();
        off[t] += v;
        __syncthreads();
    }
    int excl = off[t] - myc;
    int node = b * 256 + t;
    if (node < n) { dinv[node] = dv; rowptr[node] = base + excl; }
    if (b == nbkt - 1 && t == 0) rowptr[n] = e2;
    curs[t] = excl;
    __syncthreads();
    for (int i = base + t; i < end; i += 256) {
        uint2 r = csrR[i];
        int d = r.x & 255;
        int src = (int)(r.x >> 8);
        int p = base + atomicAdd(&curs[d], 1);
        csrF[p] = make_float2(__int_as_float(src), __uint_as_float(r.y) * dvs[d]);
    }
}

// ---- per-node src-sort of csrF segments (locality only; correctness-neutral) ----
// one thread per node, exclusive segment, LDS staging, insertion sort by src.
__global__ __launch_bounds__(64) void k_sort(float2* __restrict__ csrF,
                                             const int* __restrict__ rowptr, int n) {
    __shared__ float2 buf[64][DCAP + 1];   // +1 pad: 2-lane bank alias only (free)
    int t = threadIdx.x;
    int node = blockIdx.x * 64 + t;
    if (node >= n) return;
    int s = rowptr[node], e = rowptr[node + 1];
    int m = e - s; if (m > DCAP) m = DCAP;
    for (int j = 0; j < m; ++j) buf[t][j] = csrF[s + j];
    for (int j = 1; j < m; ++j) {
        float2 v = buf[t][j];
        int key = __float_as_int(v.x);
        int k = j - 1;
        while (k >= 0 && __float_as_int(buf[t][k].x) > key) {
            buf[t][k + 1] = buf[t][k];
            --k;
        }
        buf[t][k + 1] = v;
    }
    for (int j = 0; j < m; ++j) csrF[s + j] = buf[t][j];
}

// ---- weight transpose+convert: WT[n][k] = bf16(W[k][n]), 128x128 ----
__global__ __launch_bounds__(256) void k_wt(const float* __restrict__ W,
                                            unsigned short* __restrict__ WT) {
    int idx = blockIdx.x * 256 + threadIdx.x;      // 16384 total
    int nn = idx >> 7, k = idx & 127;
    WT[nn * 128 + k] = f2bf(W[k * 128 + nn]);      // write coalesced
}

// ---- MFMA GEMM: O[r] = bf16((H@W)[r] * dinv[r]); H fp32 or bf16; WT = W^T bf16 ----
template<typename T>
__global__ __launch_bounds__(256) void k_gemm_mfma(const T* __restrict__ H,
                                                   const unsigned short* __restrict__ WT,
                                                   const float* __restrict__ dinv,
                                                   unsigned short* __restrict__ O, int n) {
    int wv = threadIdx.x >> 6, lane = threadIdx.x & 63;
    int rowBase = blockIdx.x * 64 + wv * 16;
    int lr = lane & 15;            // A row / B col / D col within tile
    int lk = (lane >> 4) * 8;      // k offset within 32-chunk

    int arow = min(rowBase + lr, n - 1);
    bf16x8 a[4];
#pragma unroll
    for (int kk = 0; kk < 4; ++kk) {
        if constexpr (sizeof(T) == 4) {
            const float4* p = (const float4*)&H[(size_t)arow * 128 + kk * 32 + lk];
            float4 h0 = p[0], h1 = p[1];
            bf16x8 av;
            av[0] = (short)f2bf(h0.x); av[1] = (short)f2bf(h0.y);
            av[2] = (short)f2bf(h0.z); av[3] = (short)f2bf(h0.w);
            av[4] = (short)f2bf(h1.x); av[5] = (short)f2bf(h1.y);
            av[6] = (short)f2bf(h1.z); av[7] = (short)f2bf(h1.w);
            a[kk] = av;
        } else {
            a[kk] = *(const bf16x8*)&H[(size_t)arow * 128 + kk * 32 + lk];
        }
    }

    f32x4 acc[8] = {};
#pragma unroll
    for (int c = 0; c < 8; ++c) {
#pragma unroll
        for (int kk = 0; kk < 4; ++kk) {
            bf16x8 b = *(const bf16x8*)&WT[(size_t)(c * 16 + lr) * 128 + kk * 32 + lk];
            acc[c] = __builtin_amdgcn_mfma_f32_16x16x32_bf16(a[kk], b, acc[c], 0, 0, 0);
        }
    }

#pragma unroll
    for (int r = 0; r < 4; ++r) {
        int node = rowBase + (lane >> 4) * 4 + r;
        if (node < n) {
            float sc = dinv[node];
#pragma unroll
            for (int c = 0; c < 8; ++c)
                O[(size_t)node * 128 + c * 16 + lr] = f2bf(acc[c][r] * sc);
        }
    }
}

// ------- aggregation: 64 nodes/block, src-chunked w/ block barrier, fp32 accum -------
// requires csrF segments sorted by src (k_sort); degenerates to a correct full
// walk for any order since the final chunk bound is +inf and cursors only advance.
template<bool RELU>
__global__ __launch_bounds__(256) void k_agg(const uint4* __restrict__ Hw,
                                             const int* __restrict__ rowptr,
                                             const float2* __restrict__ csr,
                                             const float* __restrict__ bias,
                                             unsigned short* __restrict__ out,
                                             int n, int nch) {
    int wv = threadIdx.x >> 6, lane = threadIdx.x & 63;
    int g = lane >> 4, sl = lane & 15;
    int nodeBase = blockIdx.x * 64 + wv * 4 + g;    // + r*16, r=0..3
    int cur[4], end_[4];
    float acc[4][8];
#pragma unroll
    for (int r = 0; r < 4; ++r) {
        int node = nodeBase + r * 16;
        bool a = node < n;
        cur[r]  = a ? rowptr[node] : 0;
        end_[r] = a ? rowptr[node + 1] : 0;
#pragma unroll
        for (int j = 0; j < 8; ++j) acc[r][j] = 0.f;
    }

    for (int p = 0; p < nch; ++p) {
        unsigned bound = (p + 1 < nch) ? (unsigned)((p + 1) << CSH) : 0xFFFFFFFFu;
#pragma unroll
        for (int r = 0; r < 4; ++r) {
            int i = cur[r], e = end_[r];
            while (i < e) {
                float2 pp = csr[i];
                unsigned src = (unsigned)__float_as_int(pp.x);
                if (src >= bound) break;
                uint4 v = Hw[(size_t)src * 16 + sl];
                float w = pp.y;
                acc[r][0] += __uint_as_float(v.x << 16) * w;
                acc[r][1] += __uint_as_float(v.x & 0xFFFF0000u) * w;
                acc[r][2] += __uint_as_float(v.y << 16) * w;
                acc[r][3] += __uint_as_float(v.y & 0xFFFF0000u) * w;
                acc[r][4] += __uint_as_float(v.z << 16) * w;
                acc[r][5] += __uint_as_float(v.z & 0xFFFF0000u) * w;
                acc[r][6] += __uint_as_float(v.w << 16) * w;
                acc[r][7] += __uint_as_float(v.w & 0xFFFF0000u) * w;
                ++i;
            }
            cur[r] = i;
        }
        __syncthreads();
    }

    const float4* b4 = (const float4*)&bias[sl * 8];
    float4 b0 = b4[0], b1 = b4[1];
#pragma unroll
    for (int r = 0; r < 4; ++r) {
        int node = nodeBase + r * 16;
        if (node < n) {
            float o0 = acc[r][0] + b0.x, o1 = acc[r][1] + b0.y;
            float o2 = acc[r][2] + b0.z, o3 = acc[r][3] + b0.w;
            float o4 = acc[r][4] + b1.x, o5 = acc[r][5] + b1.y;
            float o6 = acc[r][6] + b1.z, o7 = acc[r][7] + b1.w;
            if (RELU) {
                o0 = fmaxf(o0, 0.f); o1 = fmaxf(o1, 0.f); o2 = fmaxf(o2, 0.f); o3 = fmaxf(o3, 0.f);
                o4 = fmaxf(o4, 0.f); o5 = fmaxf(o5, 0.f); o6 = fmaxf(o6, 0.f); o7 = fmaxf(o7, 0.f);
            }
            ushort8 o;
            o[0] = f2bf(o0); o[1] = f2bf(o1); o[2] = f2bf(o2); o[3] = f2bf(o3);
            o[4] = f2bf(o4); o[5] = f2bf(o5); o[6] = f2bf(o6); o[7] = f2bf(o7);
            *(ushort8*)&out[(size_t)node * 128 + sl * 8] = o;
        }
    }
}

// ---------------- fused mean-pool + final linear (bf16 input) ----------------
__device__ __forceinline__ int lower_bound_i(const int* a, int n, int key) {
    int lo = 0, hi = n;
    while (lo < hi) { int mid = (lo + hi) >> 1; if (a[mid] < key) lo = mid + 1; else hi = mid; }
    return lo;
}

__global__ void k_pool(const unsigned* __restrict__ H, const int* __restrict__ batch,
                       const float* __restrict__ Wlin, const float* __restrict__ blin,
                       float* __restrict__ out, int n) {
    int g = blockIdx.x;
    int start = lower_bound_i(batch, n, g);
    int end   = lower_bound_i(batch, n, g + 1);
    int t = threadIdx.x;
    int wid = t >> 6, lane = t & 63;
    float ax = 0.f, ay = 0.f;
    for (int i = start + wid; i < end; i += 4) {
        unsigned u = H[(size_t)i * 64 + lane];
        ax += __uint_as_float(u << 16);
        ay += __uint_as_float(u & 0xFFFF0000u);
    }
    __shared__ float ws[4][128];
    __shared__ float hg[128];
    ws[wid][lane * 2] = ax; ws[wid][lane * 2 + 1] = ay;
    __syncthreads();
    int cnt = end - start;
    float inv = 1.0f / fmaxf((float)cnt, 1.0f);
    if (t < 128) hg[t] = (ws[0][t] + ws[1][t] + ws[2][t] + ws[3][t]) * inv;
    __syncthreads();
    if (t < 16) {
        float s = blin[t];
        for (int ch = 0; ch < 128; ++ch) s += hg[ch] * Wlin[ch * 16 + t];
        out[g * 16 + t] = s;
    }
}

// ---------------- host ----------------
extern "C" void kernel_launch(void* const* d_in, const int* in_sizes, int n_in,
                              void* d_out, int out_size, void* d_ws, size_t ws_size,
                              hipStream_t stream) {
    const float* x    = (const float*)d_in[0];
    const int*   ei   = (const int*)d_in[1];
    const float* ew   = (const float*)d_in[2];
    const int*   batch= (const int*)d_in[3];
    const float* W1   = (const float*)d_in[4];
    const float* b1   = (const float*)d_in[5];
    const float* W2   = (const float*)d_in[6];
    const float* b2   = (const float*)d_in[7];
    const float* W3   = (const float*)d_in[8];
    const float* b3   = (const float*)d_in[9];
    const float* Wlin = (const float*)d_in[10];
    const float* blin = (const float*)d_in[11];
    float* out = (float*)d_out;

    int n  = in_sizes[0] / 128;
    int E  = in_sizes[2];
    int e2 = E + n;
    int G  = out_size / 16;
    const int* row = ei;
    const int* col = ei + E;

    int nbkt = (n + 255) >> 8;          // 256 nodes per bucket
    int M    = nbkt * NB;
    int nch  = ((n - 1) >> CSH) + 1;    // src chunks

    char* ws = (char*)d_ws;
    size_t off = 0;
    auto alloc = [&](size_t bytes) -> void* {
        void* p = ws + off;
        off = (off + bytes + 255) & ~255UL;
        return p;
    };
    // regionA: csrR (e2*8B) during pre; bf16 h (n*256B) after k_build
    size_t rawBytes = (size_t)e2 * 8;
    size_t hBytes   = (size_t)n * 128 * 2;
    void* regionA = alloc(rawBytes > hBytes ? rawBytes : hBytes);
    uint2*  csrR  = (uint2*)regionA;
    unsigned short* bufH = (unsigned short*)regionA;        // aliases csrR after k_build
    unsigned short* bufHw = (unsigned short*)alloc((size_t)n * 128 * 2);
    float2* csrF  = (float2*)alloc((size_t)e2 * 8);
    int*    cntA  = (int*)  alloc((size_t)M * 4);
    int*    S     = (int*)  alloc((size_t)(M + 1) * 4);
    int*    bsum  = (int*)  alloc(4096);
    float*  dinv  = (float*)alloc((size_t)n * 4);
    int*    rowptr= (int*)  alloc((size_t)(n + 1) * 4);
    unsigned short* WT1 = (unsigned short*)alloc(128 * 128 * 2);
    unsigned short* WT2 = (unsigned short*)alloc(128 * 128 * 2);
    unsigned short* WT3 = (unsigned short*)alloc(128 * 128 * 2);
    (void)ws_size;

    int per = (e2 + NB - 1) / NB;
    int nbScan = (M + SCAN_E - 1) / SCAN_E;

    // weight transpose+convert (independent; cheap)
    k_wt<<<64, 256, 0, stream>>>(W1, WT1);
    k_wt<<<64, 256, 0, stream>>>(W2, WT2);
    k_wt<<<64, 256, 0, stream>>>(W3, WT3);

    // dst counting sort + CSR build
    k_hist1<<<NB, 256, 0, stream>>>(col, E, e2, per, cntA, nbkt);
    k_scan_a<<<nbScan, SCAN_T, 0, stream>>>(cntA, M, S, bsum);
    k_scan_b<<<1, 128, 0, stream>>>(bsum, nbScan);
    k_scan_c<<<(M + 255) / 256, 256, 0, stream>>>(S, bsum, M, e2);
    k_scatter1<<<NB, 256, 0, stream>>>(row, col, ew, E, e2, per, S, csrR, nbkt);
    k_build<<<nbkt, 256, 0, stream>>>(csrR, S, n, e2, csrF, dinv, rowptr, nbkt);
    k_sort<<<(n + 63) / 64, 64, 0, stream>>>(csrF, rowptr, n);

    int gb = (n + 63) / 64;
    int ab = (n + 63) / 64;     // 64 nodes per block
    k_gemm_mfma<float><<<gb, 256, 0, stream>>>(x, WT1, dinv, bufHw, n);
    k_agg<true><<<ab, 256, 0, stream>>>((const uint4*)bufHw, rowptr, csrF, b1, bufH, n, nch);
    k_gemm_mfma<unsigned short><<<gb, 256, 0, stream>>>(bufH, WT2, dinv, bufHw, n);
    k_agg<true><<<ab, 256, 0, stream>>>((const uint4*)bufHw, rowptr, csrF, b2, bufH, n, nch);
    k_gemm_mfma<unsigned short><<<gb, 256, 0, stream>>>(bufH, WT3, dinv, bufHw, n);
    k_agg<false><<<ab, 256, 0, stream>>>((const uint4*)bufHw, rowptr, csrF, b3, bufH, n, nch);
    k_pool<<<G, 256, 0, stream>>>((const unsigned*)bufH, batch, Wlin, blin, out, n);
}

// Round 11
// 414.919 us; speedup vs baseline: 1.9795x; 1.9795x over previous
//
#include <hip/hip_runtime.h>
#include <hip/hip_bf16.h>

#define NB 256          // edge-pass blocks
#define MAXBKT 512      // supports n <= 131072

typedef __attribute__((ext_vector_type(8))) unsigned short ushort8;
typedef __attribute__((ext_vector_type(8))) short bf16x8;
typedef __attribute__((ext_vector_type(4))) float f32x4;

__device__ __forceinline__ unsigned short f2bf(float f) {
    unsigned u = __float_as_uint(f);
    unsigned r = (u + 0x7FFF + ((u >> 16) & 1)) >> 16;   // RNE
    return (unsigned short)r;
}

// ---- pass 1: per-(dstbkt, block) histogram of dst>>8 (zero global atomics) ----
__global__ __launch_bounds__(256) void k_hist1(const int* __restrict__ col, int E, int e2,
                                               int per, int* __restrict__ cnt, int nbkt) {
    __shared__ int h[MAXBKT];
    int t = threadIdx.x;
    for (int i = t; i < nbkt; i += 256) h[i] = 0;
    __syncthreads();
    int s = blockIdx.x * per, e = min(s + per, e2);
    for (int i = s + t; i < e; i += 256) {
        int dst = (i < E) ? col[i] : i - E;
        atomicAdd(&h[dst >> 8], 1);
    }
    __syncthreads();
    for (int i = t; i < nbkt; i += 256) cnt[i * NB + blockIdx.x] = h[i];
}

// ---- hierarchical exclusive scan ----
#define SCAN_T 256
#define SCAN_E 1024

__global__ void k_scan_a(const int* __restrict__ cnt, int n,
                         int* __restrict__ outp, int* __restrict__ bsum) {
    __shared__ int s[SCAN_T];
    int t = threadIdx.x, b = blockIdx.x;
    int base = b * SCAN_E + t * 4;
    int c0 = (base + 0 < n) ? cnt[base + 0] : 0;
    int c1 = (base + 1 < n) ? cnt[base + 1] : 0;
    int c2 = (base + 2 < n) ? cnt[base + 2] : 0;
    int c3 = (base + 3 < n) ? cnt[base + 3] : 0;
    int tsum = c0 + c1 + c2 + c3;
    s[t] = tsum; __syncthreads();
    for (int off = 1; off < SCAN_T; off <<= 1) {
        int v = (t >= off) ? s[t - off] : 0;
        __syncthreads();
        s[t] += v;
        __syncthreads();
    }
    int excl = s[t] - tsum;
    if (base + 0 < n) outp[base + 0] = excl;
    if (base + 1 < n) outp[base + 1] = excl + c0;
    if (base + 2 < n) outp[base + 2] = excl + c0 + c1;
    if (base + 3 < n) outp[base + 3] = excl + c0 + c1 + c2;
    if (t == 0) bsum[b] = s[SCAN_T - 1];
}

__global__ void k_scan_b(int* __restrict__ bsum, int nb) {
    __shared__ int s[128];
    int t = threadIdx.x;
    int v = (t < nb) ? bsum[t] : 0;
    s[t] = v; __syncthreads();
    for (int off = 1; off < 128; off <<= 1) {
        int u = (t >= off) ? s[t - off] : 0;
        __syncthreads();
        s[t] += u;
        __syncthreads();
    }
    if (t < nb) bsum[t] = s[t] - v;   // exclusive
}

__global__ void k_scan_c(int* __restrict__ outp, const int* __restrict__ bsum,
                         int n, int total) {
    int i = blockIdx.x * blockDim.x + threadIdx.x;
    if (i < n) outp[i] += bsum[i / SCAN_E];
    if (i == 0) outp[n] = total;
}

// ---- pass 3: scatter edges to exact dst-bucket-major slots (zero global atomics) ----
__global__ __launch_bounds__(256) void k_scatter1(const int* __restrict__ row,
                                                  const int* __restrict__ col,
                                                  const float* __restrict__ ew,
                                                  int E, int e2, int per,
                                                  const int* __restrict__ S,
                                                  uint2* __restrict__ csrR, int nbkt) {
    __shared__ int cur[MAXBKT];
    int t = threadIdx.x;
    for (int i = t; i < nbkt; i += 256) cur[i] = S[i * NB + blockIdx.x];
    __syncthreads();
    int s = blockIdx.x * per, e = min(s + per, e2);
    for (int i = s + t; i < e; i += 256) {
        int src, dst; float w;
        if (i < E) { src = row[i]; dst = col[i]; w = ew[i]; }
        else       { src = dst = i - E; w = 1.0f; }
        int slot = atomicAdd(&cur[dst >> 8], 1);
        csrR[slot] = make_uint2(((unsigned)src << 8) | (unsigned)(dst & 255),
                                __float_as_uint(w));
    }
}

// ---- pass 4: per-bucket regroup by dst; emits dinv, rowptr, final CSR ----
__global__ __launch_bounds__(256) void k_build(const uint2* __restrict__ csrR,
                                               const int* __restrict__ S,
                                               int n, int e2,
                                               float2* __restrict__ csrF,
                                               float* __restrict__ dinv,
                                               int* __restrict__ rowptr, int nbkt) {
    __shared__ int   cnt[256];
    __shared__ float wsm[256];
    __shared__ int   off[256];
    __shared__ float dvs[256];
    __shared__ int   curs[256];
    int b = blockIdx.x, t = threadIdx.x;
    cnt[t] = 0; wsm[t] = 0.f;
    __syncthreads();
    int base = S[b * NB], end = S[(b + 1) * NB];   // S[nbkt*NB] == e2
    for (int i = base + t; i < end; i += 256) {
        uint2 r = csrR[i];
        int d = r.x & 255;
        atomicAdd(&cnt[d], 1);
        atomicAdd(&wsm[d], __uint_as_float(r.y));
    }
    __syncthreads();
    int   myc = cnt[t];
    float w   = wsm[t];
    float dv  = (w > 0.f) ? rsqrtf(w) : 0.f;
    dvs[t] = dv;
    off[t] = myc;
    __syncthreads();
    for (int o = 1; o < 256; o <<= 1) {
        int v = (t >= o) ? off[t - o] : 0;
        __syncthreads();
        off[t] += v;
        __syncthreads();
    }
    int excl = off[t] - myc;
    int node = b * 256 + t;
    if (node < n) { dinv[node] = dv; rowptr[node] = base + excl; }
    if (b == nbkt - 1 && t == 0) rowptr[n] = e2;
    curs[t] = excl;
    __syncthreads();
    for (int i = base + t; i < end; i += 256) {
        uint2 r = csrR[i];
        int d = r.x & 255;
        int src = (int)(r.x >> 8);
        int p = base + atomicAdd(&curs[d], 1);
        csrF[p] = make_float2(__int_as_float(src), __uint_as_float(r.y) * dvs[d]);
    }
}

// ---- weight transpose+convert: WT[n][k] = bf16(W[k][n]), 128x128 ----
__global__ __launch_bounds__(256) void k_wt(const float* __restrict__ W,
                                            unsigned short* __restrict__ WT) {
    int idx = blockIdx.x * 256 + threadIdx.x;      // 16384 total
    int nn = idx >> 7, k = idx & 127;
    WT[nn * 128 + k] = f2bf(W[k * 128 + nn]);      // write coalesced
}

// ---- MFMA GEMM: O[r] = bf16((H@W)[r] * dinv[r]); H fp32 or bf16; WT = W^T bf16 ----
template<typename T>
__global__ __launch_bounds__(256) void k_gemm_mfma(const T* __restrict__ H,
                                                   const unsigned short* __restrict__ WT,
                                                   const float* __restrict__ dinv,
                                                   unsigned short* __restrict__ O, int n) {
    int wv = threadIdx.x >> 6, lane = threadIdx.x & 63;
    int rowBase = blockIdx.x * 64 + wv * 16;
    int lr = lane & 15;            // A row / B col / D col within tile
    int lk = (lane >> 4) * 8;      // k offset within 32-chunk

    int arow = min(rowBase + lr, n - 1);
    bf16x8 a[4];
#pragma unroll
    for (int kk = 0; kk < 4; ++kk) {
        if constexpr (sizeof(T) == 4) {
            const float4* p = (const float4*)&H[(size_t)arow * 128 + kk * 32 + lk];
            float4 h0 = p[0], h1 = p[1];
            bf16x8 av;
            av[0] = (short)f2bf(h0.x); av[1] = (short)f2bf(h0.y);
            av[2] = (short)f2bf(h0.z); av[3] = (short)f2bf(h0.w);
            av[4] = (short)f2bf(h1.x); av[5] = (short)f2bf(h1.y);
            av[6] = (short)f2bf(h1.z); av[7] = (short)f2bf(h1.w);
            a[kk] = av;
        } else {
            a[kk] = *(const bf16x8*)&H[(size_t)arow * 128 + kk * 32 + lk];
        }
    }

    f32x4 acc[8] = {};
#pragma unroll
    for (int c = 0; c < 8; ++c) {
#pragma unroll
        for (int kk = 0; kk < 4; ++kk) {
            bf16x8 b = *(const bf16x8*)&WT[(size_t)(c * 16 + lr) * 128 + kk * 32 + lk];
            acc[c] = __builtin_amdgcn_mfma_f32_16x16x32_bf16(a[kk], b, acc[c], 0, 0, 0);
        }
    }

#pragma unroll
    for (int r = 0; r < 4; ++r) {
        int node = rowBase + (lane >> 4) * 4 + r;
        if (node < n) {
            float sc = dinv[node];
#pragma unroll
            for (int c = 0; c < 8; ++c)
                O[(size_t)node * 128 + c * 16 + lr] = f2bf(acc[c][r] * sc);
        }
    }
}

// ---- fused agg(+bias+relu) -> LDS -> GEMM(WTnext) -> O (next-layer messages) ----
// block = 64 nodes. Wave wv aggregates rows wv*16..wv*16+15 (4 lane-groups x 4 serial
// nodes), stages bf16 in LDS, then runs the same MFMA tile as k_gemm_mfma from LDS.
__global__ __launch_bounds__(256) void k_agg_gemm(const uint4* __restrict__ Hw,
                                                  const int* __restrict__ rowptr,
                                                  const float2* __restrict__ csr,
                                                  const float* __restrict__ bias,
                                                  const unsigned short* __restrict__ WT,
                                                  const float* __restrict__ dinv,
                                                  unsigned short* __restrict__ O, int n) {
    __shared__ __align__(16) unsigned short lds[64][136];  // stride 272B = 16*17
    int t = threadIdx.x;
    int wv = t >> 6, lane = t & 63;
    int g = lane >> 4, sl = lane & 15;
    int nodeBase = blockIdx.x * 64 + wv * 16 + g * 4;   // + r, r = 0..3

    const float4* b4 = (const float4*)&bias[sl * 8];
    float4 bb0 = b4[0], bb1 = b4[1];

#pragma unroll
    for (int r = 0; r < 4; ++r) {
        int node = nodeBase + r;
        int s = 0, e = 0;
        if (node < n) { s = rowptr[node]; e = rowptr[node + 1]; }
        float a0 = 0.f, a1 = 0.f, a2 = 0.f, a3 = 0.f,
              a4 = 0.f, a5 = 0.f, a6 = 0.f, a7 = 0.f;
#define FMA8(V, W8) do {                                              \
    float _w = (W8);                                                  \
    a0 += __uint_as_float((V).x << 16) * _w;                          \
    a1 += __uint_as_float((V).x & 0xFFFF0000u) * _w;                  \
    a2 += __uint_as_float((V).y << 16) * _w;                          \
    a3 += __uint_as_float((V).y & 0xFFFF0000u) * _w;                  \
    a4 += __uint_as_float((V).z << 16) * _w;                          \
    a5 += __uint_as_float((V).z & 0xFFFF0000u) * _w;                  \
    a6 += __uint_as_float((V).w << 16) * _w;                          \
    a7 += __uint_as_float((V).w & 0xFFFF0000u) * _w;                  \
} while (0)
        int i = s;
        for (; i + 2 <= e; i += 2) {
            float2 p0 = csr[i], p1 = csr[i + 1];
            uint4 v0 = Hw[(size_t)__float_as_int(p0.x) * 16 + sl];
            uint4 v1 = Hw[(size_t)__float_as_int(p1.x) * 16 + sl];
            FMA8(v0, p0.y); FMA8(v1, p1.y);
        }
        if (i < e) {
            float2 pp = csr[i];
            uint4 v = Hw[(size_t)__float_as_int(pp.x) * 16 + sl];
            FMA8(v, pp.y);
        }
#undef FMA8
        a0 = fmaxf(a0 + bb0.x, 0.f); a1 = fmaxf(a1 + bb0.y, 0.f);
        a2 = fmaxf(a2 + bb0.z, 0.f); a3 = fmaxf(a3 + bb0.w, 0.f);
        a4 = fmaxf(a4 + bb1.x, 0.f); a5 = fmaxf(a5 + bb1.y, 0.f);
        a6 = fmaxf(a6 + bb1.z, 0.f); a7 = fmaxf(a7 + bb1.w, 0.f);
        ushort8 o;
        o[0] = f2bf(a0); o[1] = f2bf(a1); o[2] = f2bf(a2); o[3] = f2bf(a3);
        o[4] = f2bf(a4); o[5] = f2bf(a5); o[6] = f2bf(a6); o[7] = f2bf(a7);
        *(ushort8*)&lds[wv * 16 + g * 4 + r][sl * 8] = o;
    }
    __syncthreads();

    // --- GEMM phase: identical tile to k_gemm_mfma, A from LDS ---
    int lr = lane & 15;
    int lk = (lane >> 4) * 8;
    int rowBase = blockIdx.x * 64 + wv * 16;
    bf16x8 a[4];
#pragma unroll
    for (int kk = 0; kk < 4; ++kk)
        a[kk] = *(const bf16x8*)&lds[wv * 16 + lr][kk * 32 + lk];

    f32x4 acc[8] = {};
#pragma unroll
    for (int c = 0; c < 8; ++c) {
#pragma unroll
        for (int kk = 0; kk < 4; ++kk) {
            bf16x8 b = *(const bf16x8*)&WT[(size_t)(c * 16 + lr) * 128 + kk * 32 + lk];
            acc[c] = __builtin_amdgcn_mfma_f32_16x16x32_bf16(a[kk], b, acc[c], 0, 0, 0);
        }
    }
#pragma unroll
    for (int r = 0; r < 4; ++r) {
        int node = rowBase + (lane >> 4) * 4 + r;
        if (node < n) {
            float sc = dinv[node];
#pragma unroll
            for (int c = 0; c < 8; ++c)
                O[(size_t)node * 128 + c * 16 + lr] = f2bf(acc[c][r] * sc);
        }
    }
}

// ------- aggregation (layer 3): 16 lanes/node, 4 nodes/wave, fp32 accum, bf16 out -------
template<bool RELU>
__global__ __launch_bounds__(256) void k_agg(const uint4* __restrict__ Hw,
                                             const int* __restrict__ rowptr,
                                             const float2* __restrict__ csr,
                                             const float* __restrict__ bias,
                                             unsigned short* __restrict__ out, int n) {
    int wv = threadIdx.x >> 6, lane = threadIdx.x & 63;
    int g = lane >> 4, sl = lane & 15;
    int node = blockIdx.x * 16 + wv * 4 + g;
    bool act = node < n;
    int s = 0, e = 0;
    if (act) { s = rowptr[node]; e = rowptr[node + 1]; }
    float a0 = 0.f, a1 = 0.f, a2 = 0.f, a3 = 0.f, a4 = 0.f, a5 = 0.f, a6 = 0.f, a7 = 0.f;

#define FMA8(V, W8) do {                                              \
    float _w = (W8);                                                  \
    a0 += __uint_as_float((V).x << 16) * _w;                          \
    a1 += __uint_as_float((V).x & 0xFFFF0000u) * _w;                  \
    a2 += __uint_as_float((V).y << 16) * _w;                          \
    a3 += __uint_as_float((V).y & 0xFFFF0000u) * _w;                  \
    a4 += __uint_as_float((V).z << 16) * _w;                          \
    a5 += __uint_as_float((V).z & 0xFFFF0000u) * _w;                  \
    a6 += __uint_as_float((V).w << 16) * _w;                          \
    a7 += __uint_as_float((V).w & 0xFFFF0000u) * _w;                  \
} while (0)

    int i = s;
    for (; i + 2 <= e; i += 2) {
        float2 p0 = csr[i], p1 = csr[i + 1];
        uint4 v0 = Hw[(size_t)__float_as_int(p0.x) * 16 + sl];
        uint4 v1 = Hw[(size_t)__float_as_int(p1.x) * 16 + sl];
        FMA8(v0, p0.y); FMA8(v1, p1.y);
    }
    if (i < e) {
        float2 pp = csr[i];
        uint4 v = Hw[(size_t)__float_as_int(pp.x) * 16 + sl];
        FMA8(v, pp.y);
    }
#undef FMA8

    if (act) {
        const float4* b4 = (const float4*)&bias[sl * 8];
        float4 b0 = b4[0], b1 = b4[1];
        a0 += b0.x; a1 += b0.y; a2 += b0.z; a3 += b0.w;
        a4 += b1.x; a5 += b1.y; a6 += b1.z; a7 += b1.w;
        if (RELU) {
            a0 = fmaxf(a0, 0.f); a1 = fmaxf(a1, 0.f); a2 = fmaxf(a2, 0.f); a3 = fmaxf(a3, 0.f);
            a4 = fmaxf(a4, 0.f); a5 = fmaxf(a5, 0.f); a6 = fmaxf(a6, 0.f); a7 = fmaxf(a7, 0.f);
        }
        ushort8 o;
        o[0] = f2bf(a0); o[1] = f2bf(a1); o[2] = f2bf(a2); o[3] = f2bf(a3);
        o[4] = f2bf(a4); o[5] = f2bf(a5); o[6] = f2bf(a6); o[7] = f2bf(a7);
        *(ushort8*)&out[(size_t)node * 128 + sl * 8] = o;
    }
}

// ---------------- fused mean-pool + final linear (bf16 input) ----------------
__device__ __forceinline__ int lower_bound_i(const int* a, int n, int key) {
    int lo = 0, hi = n;
    while (lo < hi) { int mid = (lo + hi) >> 1; if (a[mid] < key) lo = mid + 1; else hi = mid; }
    return lo;
}

__global__ void k_pool(const unsigned* __restrict__ H, const int* __restrict__ batch,
                       const float* __restrict__ Wlin, const float* __restrict__ blin,
                       float* __restrict__ out, int n) {
    int g = blockIdx.x;
    int start = lower_bound_i(batch, n, g);
    int end   = lower_bound_i(batch, n, g + 1);
    int t = threadIdx.x;
    int wid = t >> 6, lane = t & 63;
    float ax = 0.f, ay = 0.f;
    for (int i = start + wid; i < end; i += 4) {
        unsigned u = H[(size_t)i * 64 + lane];
        ax += __uint_as_float(u << 16);
        ay += __uint_as_float(u & 0xFFFF0000u);
    }
    __shared__ float ws[4][128];
    __shared__ float hg[128];
    ws[wid][lane * 2] = ax; ws[wid][lane * 2 + 1] = ay;
    __syncthreads();
    int cnt = end - start;
    float inv = 1.0f / fmaxf((float)cnt, 1.0f);
    if (t < 128) hg[t] = (ws[0][t] + ws[1][t] + ws[2][t] + ws[3][t]) * inv;
    __syncthreads();
    if (t < 16) {
        float s = blin[t];
        for (int ch = 0; ch < 128; ++ch) s += hg[ch] * Wlin[ch * 16 + t];
        out[g * 16 + t] = s;
    }
}

// ---------------- host ----------------
extern "C" void kernel_launch(void* const* d_in, const int* in_sizes, int n_in,
                              void* d_out, int out_size, void* d_ws, size_t ws_size,
                              hipStream_t stream) {
    const float* x    = (const float*)d_in[0];
    const int*   ei   = (const int*)d_in[1];
    const float* ew   = (const float*)d_in[2];
    const int*   batch= (const int*)d_in[3];
    const float* W1   = (const float*)d_in[4];
    const float* b1   = (const float*)d_in[5];
    const float* W2   = (const float*)d_in[6];
    const float* b2   = (const float*)d_in[7];
    const float* W3   = (const float*)d_in[8];
    const float* b3   = (const float*)d_in[9];
    const float* Wlin = (const float*)d_in[10];
    const float* blin = (const float*)d_in[11];
    float* out = (float*)d_out;

    int n  = in_sizes[0] / 128;
    int E  = in_sizes[2];
    int e2 = E + n;
    int G  = out_size / 16;
    const int* row = ei;
    const int* col = ei + E;

    int nbkt = (n + 255) >> 8;          // 256 nodes per bucket
    int M    = nbkt * NB;

    char* ws = (char*)d_ws;
    size_t off = 0;
    auto alloc = [&](size_t bytes) -> void* {
        void* p = ws + off;
        off = (off + bytes + 255) & ~255UL;
        return p;
    };
    // regionA: csrR (e2*8B) during pre; bf16 h (n*256B) after k_build
    size_t rawBytes = (size_t)e2 * 8;
    size_t hBytes   = (size_t)n * 128 * 2;
    void* regionA = alloc(rawBytes > hBytes ? rawBytes : hBytes);
    uint2*  csrR  = (uint2*)regionA;
    unsigned short* bufH = (unsigned short*)regionA;        // aliases csrR after k_build
    unsigned short* bufA = (unsigned short*)alloc((size_t)n * 128 * 2);
    unsigned short* bufB = (unsigned short*)alloc((size_t)n * 128 * 2);
    float2* csrF  = (float2*)alloc((size_t)e2 * 8);
    int*    cntA  = (int*)  alloc((size_t)M * 4);
    int*    S     = (int*)  alloc((size_t)(M + 1) * 4);
    int*    bsum  = (int*)  alloc(4096);
    float*  dinv  = (float*)alloc((size_t)n * 4);
    int*    rowptr= (int*)  alloc((size_t)(n + 1) * 4);
    unsigned short* WT1 = (unsigned short*)alloc(128 * 128 * 2);
    unsigned short* WT2 = (unsigned short*)alloc(128 * 128 * 2);
    unsigned short* WT3 = (unsigned short*)alloc(128 * 128 * 2);
    (void)ws_size;

    int per = (e2 + NB - 1) / NB;
    int nbScan = (M + SCAN_E - 1) / SCAN_E;

    // weight transpose+convert (independent; cheap)
    k_wt<<<64, 256, 0, stream>>>(W1, WT1);
    k_wt<<<64, 256, 0, stream>>>(W2, WT2);
    k_wt<<<64, 256, 0, stream>>>(W3, WT3);

    // dst counting sort + CSR build
    k_hist1<<<NB, 256, 0, stream>>>(col, E, e2, per, cntA, nbkt);
    k_scan_a<<<nbScan, SCAN_T, 0, stream>>>(cntA, M, S, bsum);
    k_scan_b<<<1, 128, 0, stream>>>(bsum, nbScan);
    k_scan_c<<<(M + 255) / 256, 256, 0, stream>>>(S, bsum, M, e2);
    k_scatter1<<<NB, 256, 0, stream>>>(row, col, ew, E, e2, per, S, csrR, nbkt);
    k_build<<<nbkt, 256, 0, stream>>>(csrR, S, n, e2, csrF, dinv, rowptr, nbkt);

    int gb = (n + 63) / 64;
    int ab16 = (n + 15) / 16;
    k_gemm_mfma<float><<<gb, 256, 0, stream>>>(x, WT1, dinv, bufA, n);
    k_agg_gemm<<<gb, 256, 0, stream>>>((const uint4*)bufA, rowptr, csrF, b1, WT2, dinv, bufB, n);
    k_agg_gemm<<<gb, 256, 0, stream>>>((const uint4*)bufB, rowptr, csrF, b2, WT3, dinv, bufA, n);
    k_agg<false><<<ab16, 256, 0, stream>>>((const uint4*)bufA, rowptr, csrF, b3, bufH, n);
    k_pool<<<G, 256, 0, stream>>>((const unsigned*)bufH, batch, Wlin, blin, out, n);
}

// Round 12
// 388.213 us; speedup vs baseline: 2.1157x; 1.0688x over previous
//
#include <hip/hip_runtime.h>
#include <hip/hip_bf16.h>

#define NB 256          // edge-pass blocks
#define MAXBKT 512      // supports n <= 131072

typedef __attribute__((ext_vector_type(8))) unsigned short ushort8;
typedef __attribute__((ext_vector_type(8))) short bf16x8;
typedef __attribute__((ext_vector_type(4))) float f32x4;

__device__ __forceinline__ unsigned short f2bf(float f) {
    unsigned u = __float_as_uint(f);
    unsigned r = (u + 0x7FFF + ((u >> 16) & 1)) >> 16;   // RNE
    return (unsigned short)r;
}

// ---- fused: blocks [0,192) transpose W1/W2/W3 to bf16; blocks [192,192+NB) histogram dst>>8 ----
__global__ __launch_bounds__(256) void k_wt3_hist(const float* __restrict__ W1,
                                                  const float* __restrict__ W2,
                                                  const float* __restrict__ W3,
                                                  unsigned short* __restrict__ WT1,
                                                  unsigned short* __restrict__ WT2,
                                                  unsigned short* __restrict__ WT3,
                                                  const int* __restrict__ col, int E, int e2,
                                                  int per, int* __restrict__ cnt, int nbkt) {
    int b = blockIdx.x;
    if (b < 192) {
        const float* W = (b < 64) ? W1 : (b < 128) ? W2 : W3;
        unsigned short* WT = (b < 64) ? WT1 : (b < 128) ? WT2 : WT3;
        int idx = (b & 63) * 256 + threadIdx.x;
        int nn = idx >> 7, k = idx & 127;
        WT[nn * 128 + k] = f2bf(W[k * 128 + nn]);
        return;
    }
    int hb = b - 192;
    __shared__ int h[MAXBKT];
    int t = threadIdx.x;
    for (int i = t; i < nbkt; i += 256) h[i] = 0;
    __syncthreads();
    int s = hb * per, e = min(s + per, e2);
    for (int i = s + t; i < e; i += 256) {
        int dst = (i < E) ? col[i] : i - E;
        atomicAdd(&h[dst >> 8], 1);
    }
    __syncthreads();
    for (int i = t; i < nbkt; i += 256) cnt[i * NB + hb] = h[i];
}

// ---- hierarchical exclusive scan ----
#define SCAN_T 256
#define SCAN_E 1024

__global__ void k_scan_a(const int* __restrict__ cnt, int n,
                         int* __restrict__ outp, int* __restrict__ bsum) {
    __shared__ int s[SCAN_T];
    int t = threadIdx.x, b = blockIdx.x;
    int base = b * SCAN_E + t * 4;
    int c0 = (base + 0 < n) ? cnt[base + 0] : 0;
    int c1 = (base + 1 < n) ? cnt[base + 1] : 0;
    int c2 = (base + 2 < n) ? cnt[base + 2] : 0;
    int c3 = (base + 3 < n) ? cnt[base + 3] : 0;
    int tsum = c0 + c1 + c2 + c3;
    s[t] = tsum; __syncthreads();
    for (int off = 1; off < SCAN_T; off <<= 1) {
        int v = (t >= off) ? s[t - off] : 0;
        __syncthreads();
        s[t] += v;
        __syncthreads();
    }
    int excl = s[t] - tsum;
    if (base + 0 < n) outp[base + 0] = excl;
    if (base + 1 < n) outp[base + 1] = excl + c0;
    if (base + 2 < n) outp[base + 2] = excl + c0 + c1;
    if (base + 3 < n) outp[base + 3] = excl + c0 + c1 + c2;
    if (t == 0) bsum[b] = s[SCAN_T - 1];
}

__global__ void k_scan_b(int* __restrict__ bsum, int nb) {
    __shared__ int s[128];
    int t = threadIdx.x;
    int v = (t < nb) ? bsum[t] : 0;
    s[t] = v; __syncthreads();
    for (int off = 1; off < 128; off <<= 1) {
        int u = (t >= off) ? s[t - off] : 0;
        __syncthreads();
        s[t] += u;
        __syncthreads();
    }
    if (t < nb) bsum[t] = s[t] - v;   // exclusive
}

__global__ void k_scan_c(int* __restrict__ outp, const int* __restrict__ bsum,
                         int n, int total) {
    int i = blockIdx.x * blockDim.x + threadIdx.x;
    if (i < n) outp[i] += bsum[i / SCAN_E];
    if (i == 0) outp[n] = total;
}

// ---- scatter edges to exact dst-bucket-major slots (zero global atomics) ----
__global__ __launch_bounds__(256) void k_scatter1(const int* __restrict__ row,
                                                  const int* __restrict__ col,
                                                  const float* __restrict__ ew,
                                                  int E, int e2, int per,
                                                  const int* __restrict__ S,
                                                  uint2* __restrict__ csrR, int nbkt) {
    __shared__ int cur[MAXBKT];
    int t = threadIdx.x;
    for (int i = t; i < nbkt; i += 256) cur[i] = S[i * NB + blockIdx.x];
    __syncthreads();
    int s = blockIdx.x * per, e = min(s + per, e2);
    for (int i = s + t; i < e; i += 256) {
        int src, dst; float w;
        if (i < E) { src = row[i]; dst = col[i]; w = ew[i]; }
        else       { src = dst = i - E; w = 1.0f; }
        int slot = atomicAdd(&cur[dst >> 8], 1);
        csrR[slot] = make_uint2(((unsigned)src << 8) | (unsigned)(dst & 255),
                                __float_as_uint(w));
    }
}

// ---- per-bucket regroup by dst; emits dinv, rowptr, final CSR ----
__global__ __launch_bounds__(256) void k_build(const uint2* __restrict__ csrR,
                                               const int* __restrict__ S,
                                               int n, int e2,
                                               float2* __restrict__ csrF,
                                               float* __restrict__ dinv,
                                               int* __restrict__ rowptr, int nbkt) {
    __shared__ int   cnt[256];
    __shared__ float wsm[256];
    __shared__ int   off[256];
    __shared__ float dvs[256];
    __shared__ int   curs[256];
    int b = blockIdx.x, t = threadIdx.x;
    cnt[t] = 0; wsm[t] = 0.f;
    __syncthreads();
    int base = S[b * NB], end = S[(b + 1) * NB];   // S[nbkt*NB] == e2
    for (int i = base + t; i < end; i += 256) {
        uint2 r = csrR[i];
        int d = r.x & 255;
        atomicAdd(&cnt[d], 1);
        atomicAdd(&wsm[d], __uint_as_float(r.y));
    }
    __syncthreads();
    int   myc = cnt[t];
    float w   = wsm[t];
    float dv  = (w > 0.f) ? rsqrtf(w) : 0.f;
    dvs[t] = dv;
    off[t] = myc;
    __syncthreads();
    for (int o = 1; o < 256; o <<= 1) {
        int v = (t >= o) ? off[t - o] : 0;
        __syncthreads();
        off[t] += v;
        __syncthreads();
    }
    int excl = off[t] - myc;
    int node = b * 256 + t;
    if (node < n) { dinv[node] = dv; rowptr[node] = base + excl; }
    if (b == nbkt - 1 && t == 0) rowptr[n] = e2;
    curs[t] = excl;
    __syncthreads();
    for (int i = base + t; i < end; i += 256) {
        uint2 r = csrR[i];
        int d = r.x & 255;
        int src = (int)(r.x >> 8);
        int p = base + atomicAdd(&curs[d], 1);
        csrF[p] = make_float2(__int_as_float(src), __uint_as_float(r.y) * dvs[d]);
    }
}

// ---- MFMA GEMM: O[r] = bf16((H@W)[r] * dinv[r]); H fp32 or bf16; WT = W^T bf16 ----
template<typename T>
__global__ __launch_bounds__(256) void k_gemm_mfma(const T* __restrict__ H,
                                                   const unsigned short* __restrict__ WT,
                                                   const float* __restrict__ dinv,
                                                   unsigned short* __restrict__ O, int n) {
    int wv = threadIdx.x >> 6, lane = threadIdx.x & 63;
    int rowBase = blockIdx.x * 64 + wv * 16;
    int lr = lane & 15;            // A row / B col / D col within tile
    int lk = (lane >> 4) * 8;      // k offset within 32-chunk

    int arow = min(rowBase + lr, n - 1);
    bf16x8 a[4];
#pragma unroll
    for (int kk = 0; kk < 4; ++kk) {
        if constexpr (sizeof(T) == 4) {
            const float4* p = (const float4*)&H[(size_t)arow * 128 + kk * 32 + lk];
            float4 h0 = p[0], h1 = p[1];
            bf16x8 av;
            av[0] = (short)f2bf(h0.x); av[1] = (short)f2bf(h0.y);
            av[2] = (short)f2bf(h0.z); av[3] = (short)f2bf(h0.w);
            av[4] = (short)f2bf(h1.x); av[5] = (short)f2bf(h1.y);
            av[6] = (short)f2bf(h1.z); av[7] = (short)f2bf(h1.w);
            a[kk] = av;
        } else {
            a[kk] = *(const bf16x8*)&H[(size_t)arow * 128 + kk * 32 + lk];
        }
    }

    f32x4 acc[8] = {};
#pragma unroll
    for (int c = 0; c < 8; ++c) {
#pragma unroll
        for (int kk = 0; kk < 4; ++kk) {
            bf16x8 b = *(const bf16x8*)&WT[(size_t)(c * 16 + lr) * 128 + kk * 32 + lk];
            acc[c] = __builtin_amdgcn_mfma_f32_16x16x32_bf16(a[kk], b, acc[c], 0, 0, 0);
        }
    }

#pragma unroll
    for (int r = 0; r < 4; ++r) {
        int node = rowBase + (lane >> 4) * 4 + r;
        if (node < n) {
            float sc = dinv[node];
#pragma unroll
            for (int c = 0; c < 8; ++c)
                O[(size_t)node * 128 + c * 16 + lr] = f2bf(acc[c][r] * sc);
        }
    }
}

// ------- aggregation: 16 lanes/node, 4 nodes/wave, fp32 accum, bf16 out -------
// csr read as float4 (2 edges per load, 16B aligned after odd-head fix).
template<bool RELU>
__global__ __launch_bounds__(256) void k_agg(const uint4* __restrict__ Hw,
                                             const int* __restrict__ rowptr,
                                             const float2* __restrict__ csr,
                                             const float* __restrict__ bias,
                                             unsigned short* __restrict__ out, int n) {
    int wv = threadIdx.x >> 6, lane = threadIdx.x & 63;
    int g = lane >> 4, sl = lane & 15;
    int node = blockIdx.x * 16 + wv * 4 + g;
    bool act = node < n;
    int s = 0, e = 0;
    if (act) { s = rowptr[node]; e = rowptr[node + 1]; }
    float a0 = 0.f, a1 = 0.f, a2 = 0.f, a3 = 0.f, a4 = 0.f, a5 = 0.f, a6 = 0.f, a7 = 0.f;

#define FMA8(V, W8) do {                                              \
    float _w = (W8);                                                  \
    a0 += __uint_as_float((V).x << 16) * _w;                          \
    a1 += __uint_as_float((V).x & 0xFFFF0000u) * _w;                  \
    a2 += __uint_as_float((V).y << 16) * _w;                          \
    a3 += __uint_as_float((V).y & 0xFFFF0000u) * _w;                  \
    a4 += __uint_as_float((V).z << 16) * _w;                          \
    a5 += __uint_as_float((V).z & 0xFFFF0000u) * _w;                  \
    a6 += __uint_as_float((V).w << 16) * _w;                          \
    a7 += __uint_as_float((V).w & 0xFFFF0000u) * _w;                  \
} while (0)

    int i = s;
    if ((i & 1) && i < e) {                // align to 16B for float4 csr loads
        float2 pp = csr[i];
        uint4 v = Hw[(size_t)__float_as_int(pp.x) * 16 + sl];
        FMA8(v, pp.y);
        ++i;
    }
    for (; i + 2 <= e; i += 2) {
        float4 pq = *(const float4*)&csr[i];   // (src0,w0,src1,w1)
        uint4 v0 = Hw[(size_t)__float_as_int(pq.x) * 16 + sl];
        uint4 v1 = Hw[(size_t)__float_as_int(pq.z) * 16 + sl];
        FMA8(v0, pq.y); FMA8(v1, pq.w);
    }
    if (i < e) {
        float2 pp = csr[i];
        uint4 v = Hw[(size_t)__float_as_int(pp.x) * 16 + sl];
        FMA8(v, pp.y);
    }
#undef FMA8

    if (act) {
        const float4* b4 = (const float4*)&bias[sl * 8];
        float4 b0 = b4[0], b1 = b4[1];
        a0 += b0.x; a1 += b0.y; a2 += b0.z; a3 += b0.w;
        a4 += b1.x; a5 += b1.y; a6 += b1.z; a7 += b1.w;
        if (RELU) {
            a0 = fmaxf(a0, 0.f); a1 = fmaxf(a1, 0.f); a2 = fmaxf(a2, 0.f); a3 = fmaxf(a3, 0.f);
            a4 = fmaxf(a4, 0.f); a5 = fmaxf(a5, 0.f); a6 = fmaxf(a6, 0.f); a7 = fmaxf(a7, 0.f);
        }
        ushort8 o;
        o[0] = f2bf(a0); o[1] = f2bf(a1); o[2] = f2bf(a2); o[3] = f2bf(a3);
        o[4] = f2bf(a4); o[5] = f2bf(a5); o[6] = f2bf(a6); o[7] = f2bf(a7);
        *(ushort8*)&out[(size_t)node * 128 + sl * 8] = o;
    }
}

// ---------------- fused mean-pool + final linear (bf16 input) ----------------
__device__ __forceinline__ int lower_bound_i(const int* a, int n, int key) {
    int lo = 0, hi = n;
    while (lo < hi) { int mid = (lo + hi) >> 1; if (a[mid] < key) lo = mid + 1; else hi = mid; }
    return lo;
}

__global__ void k_pool(const unsigned* __restrict__ H, const int* __restrict__ batch,
                       const float* __restrict__ Wlin, const float* __restrict__ blin,
                       float* __restrict__ out, int n) {
    int g = blockIdx.x;
    int start = lower_bound_i(batch, n, g);
    int end   = lower_bound_i(batch, n, g + 1);
    int t = threadIdx.x;
    int wid = t >> 6, lane = t & 63;
    float ax = 0.f, ay = 0.f;
    for (int i = start + wid; i < end; i += 4) {
        unsigned u = H[(size_t)i * 64 + lane];
        ax += __uint_as_float(u << 16);
        ay += __uint_as_float(u & 0xFFFF0000u);
    }
    __shared__ float ws[4][128];
    __shared__ float hg[128];
    ws[wid][lane * 2] = ax; ws[wid][lane * 2 + 1] = ay;
    __syncthreads();
    int cnt = end - start;
    float inv = 1.0f / fmaxf((float)cnt, 1.0f);
    if (t < 128) hg[t] = (ws[0][t] + ws[1][t] + ws[2][t] + ws[3][t]) * inv;
    __syncthreads();
    if (t < 16) {
        float s = blin[t];
        for (int ch = 0; ch < 128; ++ch) s += hg[ch] * Wlin[ch * 16 + t];
        out[g * 16 + t] = s;
    }
}

// ---------------- host ----------------
extern "C" void kernel_launch(void* const* d_in, const int* in_sizes, int n_in,
                              void* d_out, int out_size, void* d_ws, size_t ws_size,
                              hipStream_t stream) {
    const float* x    = (const float*)d_in[0];
    const int*   ei   = (const int*)d_in[1];
    const float* ew   = (const float*)d_in[2];
    const int*   batch= (const int*)d_in[3];
    const float* W1   = (const float*)d_in[4];
    const float* b1   = (const float*)d_in[5];
    const float* W2   = (const float*)d_in[6];
    const float* b2   = (const float*)d_in[7];
    const float* W3   = (const float*)d_in[8];
    const float* b3   = (const float*)d_in[9];
    const float* Wlin = (const float*)d_in[10];
    const float* blin = (const float*)d_in[11];
    float* out = (float*)d_out;

    int n  = in_sizes[0] / 128;
    int E  = in_sizes[2];
    int e2 = E + n;
    int G  = out_size / 16;
    const int* row = ei;
    const int* col = ei + E;

    int nbkt = (n + 255) >> 8;          // 256 nodes per bucket
    int M    = nbkt * NB;

    char* ws = (char*)d_ws;
    size_t off = 0;
    auto alloc = [&](size_t bytes) -> void* {
        void* p = ws + off;
        off = (off + bytes + 255) & ~255UL;
        return p;
    };
    // regionA: csrR (e2*8B) during pre; bf16 h (n*256B) after k_build
    size_t rawBytes = (size_t)e2 * 8;
    size_t hBytes   = (size_t)n * 128 * 2;
    void* regionA = alloc(rawBytes > hBytes ? rawBytes : hBytes);
    uint2*  csrR  = (uint2*)regionA;
    unsigned short* bufH = (unsigned short*)regionA;        // aliases csrR after k_build
    unsigned short* bufHw = (unsigned short*)alloc((size_t)n * 128 * 2);
    float2* csrF  = (float2*)alloc((size_t)e2 * 8);
    int*    cntA  = (int*)  alloc((size_t)M * 4);
    int*    S     = (int*)  alloc((size_t)(M + 1) * 4);
    int*    bsum  = (int*)  alloc(4096);
    float*  dinv  = (float*)alloc((size_t)n * 4);
    int*    rowptr= (int*)  alloc((size_t)(n + 1) * 4);
    unsigned short* WT1 = (unsigned short*)alloc(128 * 128 * 2);
    unsigned short* WT2 = (unsigned short*)alloc(128 * 128 * 2);
    unsigned short* WT3 = (unsigned short*)alloc(128 * 128 * 2);
    (void)ws_size;

    int per = (e2 + NB - 1) / NB;
    int nbScan = (M + SCAN_E - 1) / SCAN_E;

    // fused weight transpose + dst histogram (all independent)
    k_wt3_hist<<<192 + NB, 256, 0, stream>>>(W1, W2, W3, WT1, WT2, WT3,
                                             col, E, e2, per, cntA, nbkt);
    k_scan_a<<<nbScan, SCAN_T, 0, stream>>>(cntA, M, S, bsum);
    k_scan_b<<<1, 128, 0, stream>>>(bsum, nbScan);
    k_scan_c<<<(M + 255) / 256, 256, 0, stream>>>(S, bsum, M, e2);
    k_scatter1<<<NB, 256, 0, stream>>>(row, col, ew, E, e2, per, S, csrR, nbkt);
    k_build<<<nbkt, 256, 0, stream>>>(csrR, S, n, e2, csrF, dinv, rowptr, nbkt);

    int gb = (n + 63) / 64;
    int ab = (n + 15) / 16;
    k_gemm_mfma<float><<<gb, 256, 0, stream>>>(x, WT1, dinv, bufHw, n);
    k_agg<true><<<ab, 256, 0, stream>>>((const uint4*)bufHw, rowptr, csrF, b1, bufH, n);
    k_gemm_mfma<unsigned short><<<gb, 256, 0, stream>>>(bufH, WT2, dinv, bufHw, n);
    k_agg<true><<<ab, 256, 0, stream>>>((const uint4*)bufHw, rowptr, csrF, b2, bufH, n);
    k_gemm_mfma<unsigned short><<<gb, 256, 0, stream>>>(bufH, WT3, dinv, bufHw, n);
    k_agg<false><<<ab, 256, 0, stream>>>((const uint4*)bufHw, rowptr, csrF, b3, bufH, n);
    k_pool<<<G, 256, 0, stream>>>((const unsigned*)bufH, batch, Wlin, blin, out, n);
}

// Round 13
// 382.784 us; speedup vs baseline: 2.1457x; 1.0142x over previous
//
#include <hip/hip_runtime.h>
#include <hip/hip_bf16.h>

#define NB 512          // edge-pass blocks
#define MAXBKT 512      // supports n <= 131072

typedef __attribute__((ext_vector_type(8))) unsigned short ushort8;
typedef __attribute__((ext_vector_type(8))) short bf16x8;
typedef __attribute__((ext_vector_type(4))) float f32x4;

__device__ __forceinline__ unsigned short f2bf(float f) {
    unsigned u = __float_as_uint(f);
    unsigned r = (u + 0x7FFF + ((u >> 16) & 1)) >> 16;   // RNE
    return (unsigned short)r;
}

// ---- fused: blocks [0,192) transpose W1/W2/W3 to bf16; blocks [192,192+NB) histogram dst>>8 ----
__global__ __launch_bounds__(256) void k_wt3_hist(const float* __restrict__ W1,
                                                  const float* __restrict__ W2,
                                                  const float* __restrict__ W3,
                                                  unsigned short* __restrict__ WT1,
                                                  unsigned short* __restrict__ WT2,
                                                  unsigned short* __restrict__ WT3,
                                                  const int* __restrict__ col, int E, int e2,
                                                  int per, int* __restrict__ cnt, int nbkt) {
    int b = blockIdx.x;
    if (b < 192) {
        const float* W = (b < 64) ? W1 : (b < 128) ? W2 : W3;
        unsigned short* WT = (b < 64) ? WT1 : (b < 128) ? WT2 : WT3;
        int idx = (b & 63) * 256 + threadIdx.x;
        int nn = idx >> 7, k = idx & 127;
        WT[nn * 128 + k] = f2bf(W[k * 128 + nn]);
        return;
    }
    int hb = b - 192;
    __shared__ int h[MAXBKT];
    int t = threadIdx.x;
    for (int i = t; i < nbkt; i += 256) h[i] = 0;
    __syncthreads();
    int s = hb * per, e = min(s + per, e2);
    for (int i = s + t; i < e; i += 256) {
        int dst = (i < E) ? col[i] : i - E;
        atomicAdd(&h[dst >> 8], 1);
    }
    __syncthreads();
    for (int i = t; i < nbkt; i += 256) cnt[i * NB + hb] = h[i];
}

// ---- hierarchical exclusive scan (2 kernels; bsum folded into consumers) ----
#define SCAN_T 256
#define SCAN_E 1024

__global__ void k_scan_a(const int* __restrict__ cnt, int n,
                         int* __restrict__ outp, int* __restrict__ bsum) {
    __shared__ int s[SCAN_T];
    int t = threadIdx.x, b = blockIdx.x;
    int base = b * SCAN_E + t * 4;
    int c0 = (base + 0 < n) ? cnt[base + 0] : 0;
    int c1 = (base + 1 < n) ? cnt[base + 1] : 0;
    int c2 = (base + 2 < n) ? cnt[base + 2] : 0;
    int c3 = (base + 3 < n) ? cnt[base + 3] : 0;
    int tsum = c0 + c1 + c2 + c3;
    s[t] = tsum; __syncthreads();
    for (int off = 1; off < SCAN_T; off <<= 1) {
        int v = (t >= off) ? s[t - off] : 0;
        __syncthreads();
        s[t] += v;
        __syncthreads();
    }
    int excl = s[t] - tsum;
    if (base + 0 < n) outp[base + 0] = excl;
    if (base + 1 < n) outp[base + 1] = excl + c0;
    if (base + 2 < n) outp[base + 2] = excl + c0 + c1;
    if (base + 3 < n) outp[base + 3] = excl + c0 + c1 + c2;
    if (t == 0) bsum[b] = s[SCAN_T - 1];
}

__global__ __launch_bounds__(256) void k_scan_b(int* __restrict__ bsum, int nb) {
    __shared__ int s[256];
    int t = threadIdx.x;
    int v = (t < nb) ? bsum[t] : 0;
    s[t] = v; __syncthreads();
    for (int off = 1; off < 256; off <<= 1) {
        int u = (t >= off) ? s[t - off] : 0;
        __syncthreads();
        s[t] += u;
        __syncthreads();
    }
    if (t < nb) bsum[t] = s[t] - v;   // exclusive
}

// ---- scatter edges to exact dst-bucket-major slots (zero global atomics) ----
// S entry adjusted inline: S[idx] + bsum[idx >> 10]
__global__ __launch_bounds__(256) void k_scatter1(const int* __restrict__ row,
                                                  const int* __restrict__ col,
                                                  const float* __restrict__ ew,
                                                  int E, int e2, int per,
                                                  const int* __restrict__ S,
                                                  const int* __restrict__ bsum,
                                                  uint2* __restrict__ csrR, int nbkt) {
    __shared__ int cur[MAXBKT];
    int t = threadIdx.x;
    for (int i = t; i < nbkt; i += 256) {
        int idx = i * NB + blockIdx.x;
        cur[i] = S[idx] + bsum[idx >> 10];
    }
    __syncthreads();
    int s = blockIdx.x * per, e = min(s + per, e2);
    for (int i = s + t; i < e; i += 256) {
        int src, dst; float w;
        if (i < E) { src = row[i]; dst = col[i]; w = ew[i]; }
        else       { src = dst = i - E; w = 1.0f; }
        int slot = atomicAdd(&cur[dst >> 8], 1);
        csrR[slot] = make_uint2(((unsigned)src << 8) | (unsigned)(dst & 255),
                                __float_as_uint(w));
    }
}

// ---- per-bucket regroup by dst; emits dinv, rowptr, final CSR ----
__global__ __launch_bounds__(256) void k_build(const uint2* __restrict__ csrR,
                                               const int* __restrict__ S,
                                               const int* __restrict__ bsum,
                                               int n, int e2,
                                               float2* __restrict__ csrF,
                                               float* __restrict__ dinv,
                                               int* __restrict__ rowptr, int nbkt) {
    __shared__ int   cnt[256];
    __shared__ float wsm[256];
    __shared__ int   off[256];
    __shared__ float dvs[256];
    __shared__ int   curs[256];
    int b = blockIdx.x, t = threadIdx.x;
    cnt[t] = 0; wsm[t] = 0.f;
    __syncthreads();
    int i0 = b * NB;
    int base = S[i0] + bsum[i0 >> 10];
    int end;
    if (b + 1 < nbkt) { int i1 = (b + 1) * NB; end = S[i1] + bsum[i1 >> 10]; }
    else end = e2;
    for (int i = base + t; i < end; i += 256) {
        uint2 r = csrR[i];
        int d = r.x & 255;
        atomicAdd(&cnt[d], 1);
        atomicAdd(&wsm[d], __uint_as_float(r.y));
    }
    __syncthreads();
    int   myc = cnt[t];
    float w   = wsm[t];
    float dv  = (w > 0.f) ? rsqrtf(w) : 0.f;
    dvs[t] = dv;
    off[t] = myc;
    __syncthreads();
    for (int o = 1; o < 256; o <<= 1) {
        int v = (t >= o) ? off[t - o] : 0;
        __syncthreads();
        off[t] += v;
        __syncthreads();
    }
    int excl = off[t] - myc;
    int node = b * 256 + t;
    if (node < n) { dinv[node] = dv; rowptr[node] = base + excl; }
    if (b == nbkt - 1 && t == 0) rowptr[n] = e2;
    curs[t] = excl;
    __syncthreads();
    for (int i = base + t; i < end; i += 256) {
        uint2 r = csrR[i];
        int d = r.x & 255;
        int src = (int)(r.x >> 8);
        int p = base + atomicAdd(&curs[d], 1);
        csrF[p] = make_float2(__int_as_float(src), __uint_as_float(r.y) * dvs[d]);
    }
}

// ---- MFMA GEMM: O[r] = bf16((H@W)[r] * dinv[r]); H fp32 or bf16; WT = W^T bf16 ----
template<typename T>
__global__ __launch_bounds__(256) void k_gemm_mfma(const T* __restrict__ H,
                                                   const unsigned short* __restrict__ WT,
                                                   const float* __restrict__ dinv,
                                                   unsigned short* __restrict__ O, int n) {
    int wv = threadIdx.x >> 6, lane = threadIdx.x & 63;
    int rowBase = blockIdx.x * 64 + wv * 16;
    int lr = lane & 15;            // A row / B col / D col within tile
    int lk = (lane >> 4) * 8;      // k offset within 32-chunk

    int arow = min(rowBase + lr, n - 1);
    bf16x8 a[4];
#pragma unroll
    for (int kk = 0; kk < 4; ++kk) {
        if constexpr (sizeof(T) == 4) {
            const float4* p = (const float4*)&H[(size_t)arow * 128 + kk * 32 + lk];
            float4 h0 = p[0], h1 = p[1];
            bf16x8 av;
            av[0] = (short)f2bf(h0.x); av[1] = (short)f2bf(h0.y);
            av[2] = (short)f2bf(h0.z); av[3] = (short)f2bf(h0.w);
            av[4] = (short)f2bf(h1.x); av[5] = (short)f2bf(h1.y);
            av[6] = (short)f2bf(h1.z); av[7] = (short)f2bf(h1.w);
            a[kk] = av;
        } else {
            a[kk] = *(const bf16x8*)&H[(size_t)arow * 128 + kk * 32 + lk];
        }
    }

    f32x4 acc[8] = {};
#pragma unroll
    for (int c = 0; c < 8; ++c) {
#pragma unroll
        for (int kk = 0; kk < 4; ++kk) {
            bf16x8 b = *(const bf16x8*)&WT[(size_t)(c * 16 + lr) * 128 + kk * 32 + lk];
            acc[c] = __builtin_amdgcn_mfma_f32_16x16x32_bf16(a[kk], b, acc[c], 0, 0, 0);
        }
    }

#pragma unroll
    for (int r = 0; r < 4; ++r) {
        int node = rowBase + (lane >> 4) * 4 + r;
        if (node < n) {
            float sc = dinv[node];
#pragma unroll
            for (int c = 0; c < 8; ++c)
                O[(size_t)node * 128 + c * 16 + lr] = f2bf(acc[c][r] * sc);
        }
    }
}

// ------- aggregation: 16 lanes/node, 4 nodes/wave, fp32 accum, bf16 out -------
template<bool RELU>
__global__ __launch_bounds__(256) void k_agg(const uint4* __restrict__ Hw,
                                             const int* __restrict__ rowptr,
                                             const float2* __restrict__ csr,
                                             const float* __restrict__ bias,
                                             unsigned short* __restrict__ out, int n) {
    int wv = threadIdx.x >> 6, lane = threadIdx.x & 63;
    int g = lane >> 4, sl = lane & 15;
    int node = blockIdx.x * 16 + wv * 4 + g;
    bool act = node < n;
    int s = 0, e = 0;
    if (act) { s = rowptr[node]; e = rowptr[node + 1]; }
    float a0 = 0.f, a1 = 0.f, a2 = 0.f, a3 = 0.f, a4 = 0.f, a5 = 0.f, a6 = 0.f, a7 = 0.f;

#define FMA8(V, W8) do {                                              \
    float _w = (W8);                                                  \
    a0 += __uint_as_float((V).x << 16) * _w;                          \
    a1 += __uint_as_float((V).x & 0xFFFF0000u) * _w;                  \
    a2 += __uint_as_float((V).y << 16) * _w;                          \
    a3 += __uint_as_float((V).y & 0xFFFF0000u) * _w;                  \
    a4 += __uint_as_float((V).z << 16) * _w;                          \
    a5 += __uint_as_float((V).z & 0xFFFF0000u) * _w;                  \
    a6 += __uint_as_float((V).w << 16) * _w;                          \
    a7 += __uint_as_float((V).w & 0xFFFF0000u) * _w;                  \
} while (0)

    int i = s;
    for (; i + 2 <= e; i += 2) {
        float2 p0 = csr[i], p1 = csr[i + 1];
        uint4 v0 = Hw[(size_t)__float_as_int(p0.x) * 16 + sl];
        uint4 v1 = Hw[(size_t)__float_as_int(p1.x) * 16 + sl];
        FMA8(v0, p0.y); FMA8(v1, p1.y);
    }
    if (i < e) {
        float2 pp = csr[i];
        uint4 v = Hw[(size_t)__float_as_int(pp.x) * 16 + sl];
        FMA8(v, pp.y);
    }
#undef FMA8

    if (act) {
        const float4* b4 = (const float4*)&bias[sl * 8];
        float4 b0 = b4[0], b1 = b4[1];
        a0 += b0.x; a1 += b0.y; a2 += b0.z; a3 += b0.w;
        a4 += b1.x; a5 += b1.y; a6 += b1.z; a7 += b1.w;
        if (RELU) {
            a0 = fmaxf(a0, 0.f); a1 = fmaxf(a1, 0.f); a2 = fmaxf(a2, 0.f); a3 = fmaxf(a3, 0.f);
            a4 = fmaxf(a4, 0.f); a5 = fmaxf(a5, 0.f); a6 = fmaxf(a6, 0.f); a7 = fmaxf(a7, 0.f);
        }
        ushort8 o;
        o[0] = f2bf(a0); o[1] = f2bf(a1); o[2] = f2bf(a2); o[3] = f2bf(a3);
        o[4] = f2bf(a4); o[5] = f2bf(a5); o[6] = f2bf(a6); o[7] = f2bf(a7);
        *(ushort8*)&out[(size_t)node * 128 + sl * 8] = o;
    }
}

// ---------------- fused mean-pool + final linear (bf16 input) ----------------
__device__ __forceinline__ int lower_bound_i(const int* a, int n, int key) {
    int lo = 0, hi = n;
    while (lo < hi) { int mid = (lo + hi) >> 1; if (a[mid] < key) lo = mid + 1; else hi = mid; }
    return lo;
}

__global__ void k_pool(const unsigned* __restrict__ H, const int* __restrict__ batch,
                       const float* __restrict__ Wlin, const float* __restrict__ blin,
                       float* __restrict__ out, int n) {
    int g = blockIdx.x;
    int start = lower_bound_i(batch, n, g);
    int end   = lower_bound_i(batch, n, g + 1);
    int t = threadIdx.x;
    int wid = t >> 6, lane = t & 63;
    float ax = 0.f, ay = 0.f;
    for (int i = start + wid; i < end; i += 4) {
        unsigned u = H[(size_t)i * 64 + lane];
        ax += __uint_as_float(u << 16);
        ay += __uint_as_float(u & 0xFFFF0000u);
    }
    __shared__ float ws[4][128];
    __shared__ float hg[128];
    ws[wid][lane * 2] = ax; ws[wid][lane * 2 + 1] = ay;
    __syncthreads();
    int cnt = end - start;
    float inv = 1.0f / fmaxf((float)cnt, 1.0f);
    if (t < 128) hg[t] = (ws[0][t] + ws[1][t] + ws[2][t] + ws[3][t]) * inv;
    __syncthreads();
    if (t < 16) {
        float s = blin[t];
        for (int ch = 0; ch < 128; ++ch) s += hg[ch] * Wlin[ch * 16 + t];
        out[g * 16 + t] = s;
    }
}

// ---------------- host ----------------
extern "C" void kernel_launch(void* const* d_in, const int* in_sizes, int n_in,
                              void* d_out, int out_size, void* d_ws, size_t ws_size,
                              hipStream_t stream) {
    const float* x    = (const float*)d_in[0];
    const int*   ei   = (const int*)d_in[1];
    const float* ew   = (const float*)d_in[2];
    const int*   batch= (const int*)d_in[3];
    const float* W1   = (const float*)d_in[4];
    const float* b1   = (const float*)d_in[5];
    const float* W2   = (const float*)d_in[6];
    const float* b2   = (const float*)d_in[7];
    const float* W3   = (const float*)d_in[8];
    const float* b3   = (const float*)d_in[9];
    const float* Wlin = (const float*)d_in[10];
    const float* blin = (const float*)d_in[11];
    float* out = (float*)d_out;

    int n  = in_sizes[0] / 128;
    int E  = in_sizes[2];
    int e2 = E + n;
    int G  = out_size / 16;
    const int* row = ei;
    const int* col = ei + E;

    int nbkt = (n + 255) >> 8;          // 256 nodes per bucket
    int M    = nbkt * NB;

    char* ws = (char*)d_ws;
    size_t off = 0;
    auto alloc = [&](size_t bytes) -> void* {
        void* p = ws + off;
        off = (off + bytes + 255) & ~255UL;
        return p;
    };
    // regionA: csrR (e2*8B) during pre; bf16 h (n*256B) after k_build
    size_t rawBytes = (size_t)e2 * 8;
    size_t hBytes   = (size_t)n * 128 * 2;
    void* regionA = alloc(rawBytes > hBytes ? rawBytes : hBytes);
    uint2*  csrR  = (uint2*)regionA;
    unsigned short* bufH = (unsigned short*)regionA;        // aliases csrR after k_build
    unsigned short* bufHw = (unsigned short*)alloc((size_t)n * 128 * 2);
    float2* csrF  = (float2*)alloc((size_t)e2 * 8);
    int*    cntA  = (int*)  alloc((size_t)M * 4);
    int*    S     = (int*)  alloc((size_t)M * 4);
    int*    bsum  = (int*)  alloc(4096);
    float*  dinv  = (float*)alloc((size_t)n * 4);
    int*    rowptr= (int*)  alloc((size_t)(n + 1) * 4);
    unsigned short* WT1 = (unsigned short*)alloc(128 * 128 * 2);
    unsigned short* WT2 = (unsigned short*)alloc(128 * 128 * 2);
    unsigned short* WT3 = (unsigned short*)alloc(128 * 128 * 2);
    (void)ws_size;

    int per = (e2 + NB - 1) / NB;
    int nbScan = (M + SCAN_E - 1) / SCAN_E;   // <= 256 for n <= 131072

    // fused weight transpose + dst histogram (all independent)
    k_wt3_hist<<<192 + NB, 256, 0, stream>>>(W1, W2, W3, WT1, WT2, WT3,
                                             col, E, e2, per, cntA, nbkt);
    k_scan_a<<<nbScan, SCAN_T, 0, stream>>>(cntA, M, S, bsum);
    k_scan_b<<<1, 256, 0, stream>>>(bsum, nbScan);
    k_scatter1<<<NB, 256, 0, stream>>>(row, col, ew, E, e2, per, S, bsum, csrR, nbkt);
    k_build<<<nbkt, 256, 0, stream>>>(csrR, S, bsum, n, e2, csrF, dinv, rowptr, nbkt);

    int gb = (n + 63) / 64;
    int ab = (n + 15) / 16;
    k_gemm_mfma<float><<<gb, 256, 0, stream>>>(x, WT1, dinv, bufHw, n);
    k_agg<true><<<ab, 256, 0, stream>>>((const uint4*)bufHw, rowptr, csrF, b1, bufH, n);
    k_gemm_mfma<unsigned short><<<gb, 256, 0, stream>>>(bufH, WT2, dinv, bufHw, n);
    k_agg<true><<<ab, 256, 0, stream>>>((const uint4*)bufHw, rowptr, csrF, b2, bufH, n);
    k_gemm_mfma<unsigned short><<<gb, 256, 0, stream>>>(bufH, WT3, dinv, bufHw, n);
    k_agg<false><<<ab, 256, 0, stream>>>((const uint4*)bufHw, rowptr, csrF, b3, bufH, n);
    k_pool<<<G, 256, 0, stream>>>((const unsigned*)bufH, batch, Wlin, blin, out, n);
}

// Round 14
// 300.972 us; speedup vs baseline: 2.7289x; 1.2718x over previous
//
#include <hip/hip_runtime.h>
#include <hip/hip_bf16.h>

#define NB 512          // edge-pass blocks
#define MAXBKT 512      // supports n <= 131072
#define PB 4            // blocks per graph in fused agg3+pool

typedef __attribute__((ext_vector_type(8))) unsigned short ushort8;
typedef __attribute__((ext_vector_type(8))) short bf16x8;
typedef __attribute__((ext_vector_type(4))) float f32x4;

__device__ __forceinline__ unsigned short f2bf(float f) {
    unsigned u = __float_as_uint(f);
    unsigned r = (u + 0x7FFF + ((u >> 16) & 1)) >> 16;   // RNE
    return (unsigned short)r;
}

// ---- fused setup: [0,64) WT1, [64,128) WT2, [128,136) WLT=bf16(W3@Wlin)^T, rest: dst hist ----
__global__ __launch_bounds__(256) void k_wt3_hist(const float* __restrict__ W1,
                                                  const float* __restrict__ W2,
                                                  const float* __restrict__ W3,
                                                  const float* __restrict__ Wlin,
                                                  unsigned short* __restrict__ WT1,
                                                  unsigned short* __restrict__ WT2,
                                                  unsigned short* __restrict__ WLT,
                                                  const int* __restrict__ col, int E, int e2,
                                                  int per, int* __restrict__ cnt, int nbkt) {
    int b = blockIdx.x;
    if (b < 128) {
        const float* W = (b < 64) ? W1 : W2;
        unsigned short* WT = (b < 64) ? WT1 : WT2;
        int idx = (b & 63) * 256 + threadIdx.x;
        int nn = idx >> 7, k = idx & 127;
        WT[nn * 128 + k] = f2bf(W[k * 128 + nn]);
        return;
    }
    if (b < 136) {
        // WLT[c*128 + k] = bf16( sum_j W3[k][j] * Wlin[j][c] ), c<16, k<128
        int idx = (b - 128) * 256 + threadIdx.x;     // 2048 total
        int c = idx >> 7, k = idx & 127;
        float s = 0.f;
        for (int j = 0; j < 128; ++j) s += W3[k * 128 + j] * Wlin[j * 16 + c];
        WLT[c * 128 + k] = f2bf(s);
        return;
    }
    int hb = b - 136;
    __shared__ int h[MAXBKT];
    int t = threadIdx.x;
    for (int i = t; i < nbkt; i += 256) h[i] = 0;
    __syncthreads();
    int s = hb * per, e = min(s + per, e2);
    for (int i = s + t; i < e; i += 256) {
        int dst = (i < E) ? col[i] : i - E;
        atomicAdd(&h[dst >> 8], 1);
    }
    __syncthreads();
    for (int i = t; i < nbkt; i += 256) cnt[i * NB + hb] = h[i];
}

// ---- hierarchical exclusive scan (2 kernels; bsum folded into consumers) ----
#define SCAN_T 256
#define SCAN_E 1024

__global__ void k_scan_a(const int* __restrict__ cnt, int n,
                         int* __restrict__ outp, int* __restrict__ bsum) {
    __shared__ int s[SCAN_T];
    int t = threadIdx.x, b = blockIdx.x;
    int base = b * SCAN_E + t * 4;
    int c0 = (base + 0 < n) ? cnt[base + 0] : 0;
    int c1 = (base + 1 < n) ? cnt[base + 1] : 0;
    int c2 = (base + 2 < n) ? cnt[base + 2] : 0;
    int c3 = (base + 3 < n) ? cnt[base + 3] : 0;
    int tsum = c0 + c1 + c2 + c3;
    s[t] = tsum; __syncthreads();
    for (int off = 1; off < SCAN_T; off <<= 1) {
        int v = (t >= off) ? s[t - off] : 0;
        __syncthreads();
        s[t] += v;
        __syncthreads();
    }
    int excl = s[t] - tsum;
    if (base + 0 < n) outp[base + 0] = excl;
    if (base + 1 < n) outp[base + 1] = excl + c0;
    if (base + 2 < n) outp[base + 2] = excl + c0 + c1;
    if (base + 3 < n) outp[base + 3] = excl + c0 + c1 + c2;
    if (t == 0) bsum[b] = s[SCAN_T - 1];
}

__global__ __launch_bounds__(256) void k_scan_b(int* __restrict__ bsum, int nb) {
    __shared__ int s[256];
    int t = threadIdx.x;
    int v = (t < nb) ? bsum[t] : 0;
    s[t] = v; __syncthreads();
    for (int off = 1; off < 256; off <<= 1) {
        int u = (t >= off) ? s[t - off] : 0;
        __syncthreads();
        s[t] += u;
        __syncthreads();
    }
    if (t < nb) bsum[t] = s[t] - v;   // exclusive
}

// ---- scatter edges to exact dst-bucket-major slots (zero global atomics) ----
__global__ __launch_bounds__(256) void k_scatter1(const int* __restrict__ row,
                                                  const int* __restrict__ col,
                                                  const float* __restrict__ ew,
                                                  int E, int e2, int per,
                                                  const int* __restrict__ S,
                                                  const int* __restrict__ bsum,
                                                  uint2* __restrict__ csrR, int nbkt) {
    __shared__ int cur[MAXBKT];
    int t = threadIdx.x;
    for (int i = t; i < nbkt; i += 256) {
        int idx = i * NB + blockIdx.x;
        cur[i] = S[idx] + bsum[idx >> 10];
    }
    __syncthreads();
    int s = blockIdx.x * per, e = min(s + per, e2);
    for (int i = s + t; i < e; i += 256) {
        int src, dst; float w;
        if (i < E) { src = row[i]; dst = col[i]; w = ew[i]; }
        else       { src = dst = i - E; w = 1.0f; }
        int slot = atomicAdd(&cur[dst >> 8], 1);
        csrR[slot] = make_uint2(((unsigned)src << 8) | (unsigned)(dst & 255),
                                __float_as_uint(w));
    }
}

// ---- per-bucket regroup by dst; emits dinv, rowptr, final CSR ----
__global__ __launch_bounds__(256) void k_build(const uint2* __restrict__ csrR,
                                               const int* __restrict__ S,
                                               const int* __restrict__ bsum,
                                               int n, int e2,
                                               float2* __restrict__ csrF,
                                               float* __restrict__ dinv,
                                               int* __restrict__ rowptr, int nbkt) {
    __shared__ int   cnt[256];
    __shared__ float wsm[256];
    __shared__ int   off[256];
    __shared__ float dvs[256];
    __shared__ int   curs[256];
    int b = blockIdx.x, t = threadIdx.x;
    cnt[t] = 0; wsm[t] = 0.f;
    __syncthreads();
    int i0 = b * NB;
    int base = S[i0] + bsum[i0 >> 10];
    int end;
    if (b + 1 < nbkt) { int i1 = (b + 1) * NB; end = S[i1] + bsum[i1 >> 10]; }
    else end = e2;
    for (int i = base + t; i < end; i += 256) {
        uint2 r = csrR[i];
        int d = r.x & 255;
        atomicAdd(&cnt[d], 1);
        atomicAdd(&wsm[d], __uint_as_float(r.y));
    }
    __syncthreads();
    int   myc = cnt[t];
    float w   = wsm[t];
    float dv  = (w > 0.f) ? rsqrtf(w) : 0.f;
    dvs[t] = dv;
    off[t] = myc;
    __syncthreads();
    for (int o = 1; o < 256; o <<= 1) {
        int v = (t >= o) ? off[t - o] : 0;
        __syncthreads();
        off[t] += v;
        __syncthreads();
    }
    int excl = off[t] - myc;
    int node = b * 256 + t;
    if (node < n) { dinv[node] = dv; rowptr[node] = base + excl; }
    if (b == nbkt - 1 && t == 0) rowptr[n] = e2;
    curs[t] = excl;
    __syncthreads();
    for (int i = base + t; i < end; i += 256) {
        uint2 r = csrR[i];
        int d = r.x & 255;
        int src = (int)(r.x >> 8);
        int p = base + atomicAdd(&curs[d], 1);
        csrF[p] = make_float2(__int_as_float(src), __uint_as_float(r.y) * dvs[d]);
    }
}

// ---- MFMA GEMM: O[r] = bf16((H@W)[r] * dinv[r]); H fp32 or bf16; WT = W^T bf16 ----
template<typename T>
__global__ __launch_bounds__(256) void k_gemm_mfma(const T* __restrict__ H,
                                                   const unsigned short* __restrict__ WT,
                                                   const float* __restrict__ dinv,
                                                   unsigned short* __restrict__ O, int n) {
    int wv = threadIdx.x >> 6, lane = threadIdx.x & 63;
    int rowBase = blockIdx.x * 64 + wv * 16;
    int lr = lane & 15;
    int lk = (lane >> 4) * 8;

    int arow = min(rowBase + lr, n - 1);
    bf16x8 a[4];
#pragma unroll
    for (int kk = 0; kk < 4; ++kk) {
        if constexpr (sizeof(T) == 4) {
            const float4* p = (const float4*)&H[(size_t)arow * 128 + kk * 32 + lk];
            float4 h0 = p[0], h1 = p[1];
            bf16x8 av;
            av[0] = (short)f2bf(h0.x); av[1] = (short)f2bf(h0.y);
            av[2] = (short)f2bf(h0.z); av[3] = (short)f2bf(h0.w);
            av[4] = (short)f2bf(h1.x); av[5] = (short)f2bf(h1.y);
            av[6] = (short)f2bf(h1.z); av[7] = (short)f2bf(h1.w);
            a[kk] = av;
        } else {
            a[kk] = *(const bf16x8*)&H[(size_t)arow * 128 + kk * 32 + lk];
        }
    }

    f32x4 acc[8] = {};
#pragma unroll
    for (int c = 0; c < 8; ++c) {
#pragma unroll
        for (int kk = 0; kk < 4; ++kk) {
            bf16x8 b = *(const bf16x8*)&WT[(size_t)(c * 16 + lr) * 128 + kk * 32 + lk];
            acc[c] = __builtin_amdgcn_mfma_f32_16x16x32_bf16(a[kk], b, acc[c], 0, 0, 0);
        }
    }

#pragma unroll
    for (int r = 0; r < 4; ++r) {
        int node = rowBase + (lane >> 4) * 4 + r;
        if (node < n) {
            float sc = dinv[node];
#pragma unroll
            for (int c = 0; c < 8; ++c)
                O[(size_t)node * 128 + c * 16 + lr] = f2bf(acc[c][r] * sc);
        }
    }
}

// ---- layer-3 folded GEMM: P[n][16] fp32 = (H2 @ (W3·Wlin)) * dinv[row]; H2 bf16 ----
__global__ __launch_bounds__(256) void k_gemmP(const unsigned short* __restrict__ H,
                                               const unsigned short* __restrict__ WLT,
                                               const float* __restrict__ dinv,
                                               float* __restrict__ P, int n) {
    int wv = threadIdx.x >> 6, lane = threadIdx.x & 63;
    int rowBase = blockIdx.x * 64 + wv * 16;
    int lr = lane & 15;
    int lk = (lane >> 4) * 8;

    int arow = min(rowBase + lr, n - 1);
    f32x4 acc = {};
#pragma unroll
    for (int kk = 0; kk < 4; ++kk) {
        bf16x8 a = *(const bf16x8*)&H[(size_t)arow * 128 + kk * 32 + lk];
        bf16x8 b = *(const bf16x8*)&WLT[(size_t)lr * 128 + kk * 32 + lk];
        acc = __builtin_amdgcn_mfma_f32_16x16x32_bf16(a, b, acc, 0, 0, 0);
    }
#pragma unroll
    for (int r = 0; r < 4; ++r) {
        int node = rowBase + (lane >> 4) * 4 + r;
        if (node < n) P[(size_t)node * 16 + lr] = acc[r] * dinv[node];
    }
}

// ------- aggregation (layers 1,2): 16 lanes/node, 4 nodes/wave, fp32 accum, bf16 out -------
template<bool RELU>
__global__ __launch_bounds__(256) void k_agg(const uint4* __restrict__ Hw,
                                             const int* __restrict__ rowptr,
                                             const float2* __restrict__ csr,
                                             const float* __restrict__ bias,
                                             unsigned short* __restrict__ out, int n) {
    int wv = threadIdx.x >> 6, lane = threadIdx.x & 63;
    int g = lane >> 4, sl = lane & 15;
    int node = blockIdx.x * 16 + wv * 4 + g;
    bool act = node < n;
    int s = 0, e = 0;
    if (act) { s = rowptr[node]; e = rowptr[node + 1]; }
    float a0 = 0.f, a1 = 0.f, a2 = 0.f, a3 = 0.f, a4 = 0.f, a5 = 0.f, a6 = 0.f, a7 = 0.f;

#define FMA8(V, W8) do {                                              \
    float _w = (W8);                                                  \
    a0 += __uint_as_float((V).x << 16) * _w;                          \
    a1 += __uint_as_float((V).x & 0xFFFF0000u) * _w;                  \
    a2 += __uint_as_float((V).y << 16) * _w;                          \
    a3 += __uint_as_float((V).y & 0xFFFF0000u) * _w;                  \
    a4 += __uint_as_float((V).z << 16) * _w;                          \
    a5 += __uint_as_float((V).z & 0xFFFF0000u) * _w;                  \
    a6 += __uint_as_float((V).w << 16) * _w;                          \
    a7 += __uint_as_float((V).w & 0xFFFF0000u) * _w;                  \
} while (0)

    int i = s;
    for (; i + 2 <= e; i += 2) {
        float2 p0 = csr[i], p1 = csr[i + 1];
        uint4 v0 = Hw[(size_t)__float_as_int(p0.x) * 16 + sl];
        uint4 v1 = Hw[(size_t)__float_as_int(p1.x) * 16 + sl];
        FMA8(v0, p0.y); FMA8(v1, p1.y);
    }
    if (i < e) {
        float2 pp = csr[i];
        uint4 v = Hw[(size_t)__float_as_int(pp.x) * 16 + sl];
        FMA8(v, pp.y);
    }
#undef FMA8

    if (act) {
        const float4* b4 = (const float4*)&bias[sl * 8];
        float4 b0 = b4[0], b1 = b4[1];
        a0 += b0.x; a1 += b0.y; a2 += b0.z; a3 += b0.w;
        a4 += b1.x; a5 += b1.y; a6 += b1.z; a7 += b1.w;
        if (RELU) {
            a0 = fmaxf(a0, 0.f); a1 = fmaxf(a1, 0.f); a2 = fmaxf(a2, 0.f); a3 = fmaxf(a3, 0.f);
            a4 = fmaxf(a4, 0.f); a5 = fmaxf(a5, 0.f); a6 = fmaxf(a6, 0.f); a7 = fmaxf(a7, 0.f);
        }
        ushort8 o;
        o[0] = f2bf(a0); o[1] = f2bf(a1); o[2] = f2bf(a2); o[3] = f2bf(a3);
        o[4] = f2bf(a4); o[5] = f2bf(a5); o[6] = f2bf(a6); o[7] = f2bf(a7);
        *(ushort8*)&out[(size_t)node * 128 + sl * 8] = o;
    }
}

// ---------------- fused layer-3 agg + pool (linear path): per-graph edge-sum of P ----------------
__device__ __forceinline__ int lower_bound_i(const int* a, int n, int key) {
    int lo = 0, hi = n;
    while (lo < hi) { int mid = (lo + hi) >> 1; if (a[mid] < key) lo = mid + 1; else hi = mid; }
    return lo;
}

// PB blocks per graph; each walks a contiguous edge subrange (batch sorted => graph edges contiguous)
__global__ __launch_bounds__(256) void k_agg_pool(const float4* __restrict__ P4,
                                                  const int* __restrict__ rowptr,
                                                  const float2* __restrict__ csr,
                                                  const int* __restrict__ batch,
                                                  int n, float* __restrict__ partial) {
    int g = blockIdx.x >> 2, part = blockIdx.x & (PB - 1);
    int start = lower_bound_i(batch, n, g);
    int end   = lower_bound_i(batch, n, g + 1);
    int cn = end - start;
    int ns = start + (cn * part) / PB;
    int ne = start + (cn * (part + 1)) / PB;
    int es = rowptr[ns], ee = rowptr[ne];
    int t = threadIdx.x, grp = t >> 2, sl4 = t & 3;   // 64 groups x 4 lanes
    float a0 = 0.f, a1 = 0.f, a2 = 0.f, a3 = 0.f;
    int i = es + grp;
    for (; i + 64 < ee; i += 128) {
        float2 p0 = csr[i], p1 = csr[i + 64];
        float4 v0 = P4[(size_t)__float_as_int(p0.x) * 4 + sl4];
        float4 v1 = P4[(size_t)__float_as_int(p1.x) * 4 + sl4];
        a0 += v0.x * p0.y; a1 += v0.y * p0.y; a2 += v0.z * p0.y; a3 += v0.w * p0.y;
        a0 += v1.x * p1.y; a1 += v1.y * p1.y; a2 += v1.z * p1.y; a3 += v1.w * p1.y;
    }
    if (i < ee) {
        float2 pp = csr[i];
        float4 v = P4[(size_t)__float_as_int(pp.x) * 4 + sl4];
        a0 += v.x * pp.y; a1 += v.y * pp.y; a2 += v.z * pp.y; a3 += v.w * pp.y;
    }
    __shared__ float red[64][20];
    *(float4*)&red[grp][sl4 * 4] = make_float4(a0, a1, a2, a3);
    __syncthreads();
    if (t < 16) {
        float s = 0.f;
        for (int k2 = 0; k2 < 64; ++k2) s += red[k2][t];
        partial[(size_t)blockIdx.x * 16 + t] = s;
    }
}

// final: reduce PB partials, /cnt, + b3@Wlin + blin
__global__ void k_poolfin(const float* __restrict__ partial, const int* __restrict__ batch,
                          const float* __restrict__ b3, const float* __restrict__ Wlin,
                          const float* __restrict__ blin, float* __restrict__ out, int n) {
    int g = blockIdx.x, t = threadIdx.x;
    if (t >= 16) return;
    int start = lower_bound_i(batch, n, g);
    int end   = lower_bound_i(batch, n, g + 1);
    int cn = end - start;
    float s = partial[(size_t)(g * PB + 0) * 16 + t] + partial[(size_t)(g * PB + 1) * 16 + t]
            + partial[(size_t)(g * PB + 2) * 16 + t] + partial[(size_t)(g * PB + 3) * 16 + t];
    float bw = 0.f;
    for (int ch = 0; ch < 128; ++ch) bw += b3[ch] * Wlin[ch * 16 + t];
    out[g * 16 + t] = (cn > 0) ? s / (float)cn + bw + blin[t] : blin[t];
}

// ---------------- host ----------------
extern "C" void kernel_launch(void* const* d_in, const int* in_sizes, int n_in,
                              void* d_out, int out_size, void* d_ws, size_t ws_size,
                              hipStream_t stream) {
    const float* x    = (const float*)d_in[0];
    const int*   ei   = (const int*)d_in[1];
    const float* ew   = (const float*)d_in[2];
    const int*   batch= (const int*)d_in[3];
    const float* W1   = (const float*)d_in[4];
    const float* b1   = (const float*)d_in[5];
    const float* W2   = (const float*)d_in[6];
    const float* b2   = (const float*)d_in[7];
    const float* W3   = (const float*)d_in[8];
    const float* b3   = (const float*)d_in[9];
    const float* Wlin = (const float*)d_in[10];
    const float* blin = (const float*)d_in[11];
    float* out = (float*)d_out;

    int n  = in_sizes[0] / 128;
    int E  = in_sizes[2];
    int e2 = E + n;
    int G  = out_size / 16;
    const int* row = ei;
    const int* col = ei + E;

    int nbkt = (n + 255) >> 8;          // 256 nodes per bucket
    int M    = nbkt * NB;

    char* ws = (char*)d_ws;
    size_t off = 0;
    auto alloc = [&](size_t bytes) -> void* {
        void* p = ws + off;
        off = (off + bytes + 255) & ~255UL;
        return p;
    };
    // regionA: csrR (e2*8B) during pre; bf16 h (n*256B) after k_build
    size_t rawBytes = (size_t)e2 * 8;
    size_t hBytes   = (size_t)n * 128 * 2;
    void* regionA = alloc(rawBytes > hBytes ? rawBytes : hBytes);
    uint2*  csrR  = (uint2*)regionA;
    unsigned short* bufH = (unsigned short*)regionA;        // aliases csrR after k_build
    unsigned short* bufHw = (unsigned short*)alloc((size_t)n * 128 * 2);
    float2* csrF  = (float2*)alloc((size_t)e2 * 8);
    int*    cntA  = (int*)  alloc((size_t)M * 4);
    int*    S     = (int*)  alloc((size_t)M * 4);
    int*    bsum  = (int*)  alloc(4096);
    float*  dinv  = (float*)alloc((size_t)n * 4);
    int*    rowptr= (int*)  alloc((size_t)(n + 1) * 4);
    unsigned short* WT1 = (unsigned short*)alloc(128 * 128 * 2);
    unsigned short* WT2 = (unsigned short*)alloc(128 * 128 * 2);
    unsigned short* WLT = (unsigned short*)alloc(16 * 128 * 2);
    float*  P       = (float*)alloc((size_t)n * 16 * 4);
    float*  partial = (float*)alloc((size_t)G * PB * 16 * 4);
    (void)ws_size;

    int per = (e2 + NB - 1) / NB;
    int nbScan = (M + SCAN_E - 1) / SCAN_E;   // <= 256 for n <= 131072

    // fused weight prep + dst histogram (all independent)
    k_wt3_hist<<<136 + NB, 256, 0, stream>>>(W1, W2, W3, Wlin, WT1, WT2, WLT,
                                             col, E, e2, per, cntA, nbkt);
    k_scan_a<<<nbScan, SCAN_T, 0, stream>>>(cntA, M, S, bsum);
    k_scan_b<<<1, 256, 0, stream>>>(bsum, nbScan);
    k_scatter1<<<NB, 256, 0, stream>>>(row, col, ew, E, e2, per, S, bsum, csrR, nbkt);
    k_build<<<nbkt, 256, 0, stream>>>(csrR, S, bsum, n, e2, csrF, dinv, rowptr, nbkt);

    int gb = (n + 63) / 64;
    int ab = (n + 15) / 16;
    k_gemm_mfma<float><<<gb, 256, 0, stream>>>(x, WT1, dinv, bufHw, n);
    k_agg<true><<<ab, 256, 0, stream>>>((const uint4*)bufHw, rowptr, csrF, b1, bufH, n);
    k_gemm_mfma<unsigned short><<<gb, 256, 0, stream>>>(bufH, WT2, dinv, bufHw, n);
    k_agg<true><<<ab, 256, 0, stream>>>((const uint4*)bufHw, rowptr, csrF, b2, bufH, n);
    k_gemmP<<<gb, 256, 0, stream>>>(bufH, WLT, dinv, P, n);
    k_agg_pool<<<G * PB, 256, 0, stream>>>((const float4*)P, rowptr, csrF, batch, n, partial);
    k_poolfin<<<G, 64, 0, stream>>>(partial, batch, b3, Wlin, blin, out, n);
}

// Round 15
// 279.491 us; speedup vs baseline: 2.9387x; 1.0769x over previous
//
#include <hip/hip_runtime.h>
#include <hip/hip_bf16.h>

#define NB 512          // edge-pass blocks
#define MAXBKT 512      // supports n <= 131072
#define PB 4            // blocks per graph in fused agg3+pool

typedef __attribute__((ext_vector_type(8))) unsigned short ushort8;
typedef __attribute__((ext_vector_type(8))) short bf16x8;
typedef __attribute__((ext_vector_type(4))) float f32x4;

__device__ __forceinline__ unsigned short f2bf(float f) {
    unsigned u = __float_as_uint(f);
    unsigned r = (u + 0x7FFF + ((u >> 16) & 1)) >> 16;   // RNE
    return (unsigned short)r;
}

// ---- fused setup: [0,64) WT1, [64,128) WT2, [128,136) WLT=bf16(W3@Wlin)^T, rest: dst hist ----
__global__ __launch_bounds__(256) void k_wt3_hist(const float* __restrict__ W1,
                                                  const float* __restrict__ W2,
                                                  const float* __restrict__ W3,
                                                  const float* __restrict__ Wlin,
                                                  unsigned short* __restrict__ WT1,
                                                  unsigned short* __restrict__ WT2,
                                                  unsigned short* __restrict__ WLT,
                                                  const int* __restrict__ col, int E, int e2,
                                                  int per, int* __restrict__ cnt, int nbkt) {
    int b = blockIdx.x;
    if (b < 128) {
        const float* W = (b < 64) ? W1 : W2;
        unsigned short* WT = (b < 64) ? WT1 : WT2;
        int idx = (b & 63) * 256 + threadIdx.x;
        int nn = idx >> 7, k = idx & 127;
        WT[nn * 128 + k] = f2bf(W[k * 128 + nn]);
        return;
    }
    if (b < 136) {
        // WLT[c*128 + k] = bf16( sum_j W3[k][j] * Wlin[j][c] ), c<16, k<128
        int idx = (b - 128) * 256 + threadIdx.x;     // 2048 total
        int c = idx >> 7, k = idx & 127;
        float s = 0.f;
        for (int j = 0; j < 128; ++j) s += W3[k * 128 + j] * Wlin[j * 16 + c];
        WLT[c * 128 + k] = f2bf(s);
        return;
    }
    int hb = b - 136;
    __shared__ int h[MAXBKT];
    int t = threadIdx.x;
    for (int i = t; i < nbkt; i += 256) h[i] = 0;
    __syncthreads();
    int s = hb * per, e = min(s + per, e2);
    for (int i = s + t; i < e; i += 256) {
        int dst = (i < E) ? col[i] : i - E;
        atomicAdd(&h[dst >> 8], 1);
    }
    __syncthreads();
    for (int i = t; i < nbkt; i += 256) cnt[i * NB + hb] = h[i];
}

// ---- hierarchical exclusive scan (2 kernels; bsum folded into consumers) ----
#define SCAN_T 256
#define SCAN_E 1024

__global__ void k_scan_a(const int* __restrict__ cnt, int n,
                         int* __restrict__ outp, int* __restrict__ bsum) {
    __shared__ int s[SCAN_T];
    int t = threadIdx.x, b = blockIdx.x;
    int base = b * SCAN_E + t * 4;
    int c0 = (base + 0 < n) ? cnt[base + 0] : 0;
    int c1 = (base + 1 < n) ? cnt[base + 1] : 0;
    int c2 = (base + 2 < n) ? cnt[base + 2] : 0;
    int c3 = (base + 3 < n) ? cnt[base + 3] : 0;
    int tsum = c0 + c1 + c2 + c3;
    s[t] = tsum; __syncthreads();
    for (int off = 1; off < SCAN_T; off <<= 1) {
        int v = (t >= off) ? s[t - off] : 0;
        __syncthreads();
        s[t] += v;
        __syncthreads();
    }
    int excl = s[t] - tsum;
    if (base + 0 < n) outp[base + 0] = excl;
    if (base + 1 < n) outp[base + 1] = excl + c0;
    if (base + 2 < n) outp[base + 2] = excl + c0 + c1;
    if (base + 3 < n) outp[base + 3] = excl + c0 + c1 + c2;
    if (t == 0) bsum[b] = s[SCAN_T - 1];
}

__global__ __launch_bounds__(256) void k_scan_b(int* __restrict__ bsum, int nb) {
    __shared__ int s[256];
    int t = threadIdx.x;
    int v = (t < nb) ? bsum[t] : 0;
    s[t] = v; __syncthreads();
    for (int off = 1; off < 256; off <<= 1) {
        int u = (t >= off) ? s[t - off] : 0;
        __syncthreads();
        s[t] += u;
        __syncthreads();
    }
    if (t < nb) bsum[t] = s[t] - v;   // exclusive
}

// ---- scatter edges to exact dst-bucket-major slots (zero global atomics) ----
__global__ __launch_bounds__(256) void k_scatter1(const int* __restrict__ row,
                                                  const int* __restrict__ col,
                                                  const float* __restrict__ ew,
                                                  int E, int e2, int per,
                                                  const int* __restrict__ S,
                                                  const int* __restrict__ bsum,
                                                  uint2* __restrict__ csrR, int nbkt) {
    __shared__ int cur[MAXBKT];
    int t = threadIdx.x;
    for (int i = t; i < nbkt; i += 256) {
        int idx = i * NB + blockIdx.x;
        cur[i] = S[idx] + bsum[idx >> 10];
    }
    __syncthreads();
    int s = blockIdx.x * per, e = min(s + per, e2);
    for (int i = s + t; i < e; i += 256) {
        int src, dst; float w;
        if (i < E) { src = row[i]; dst = col[i]; w = ew[i]; }
        else       { src = dst = i - E; w = 1.0f; }
        int slot = atomicAdd(&cur[dst >> 8], 1);
        csrR[slot] = make_uint2(((unsigned)src << 8) | (unsigned)(dst & 255),
                                __float_as_uint(w));
    }
}

// ---- per-bucket regroup by dst; emits dinv, rowptr, final CSR ----
__global__ __launch_bounds__(256) void k_build(const uint2* __restrict__ csrR,
                                               const int* __restrict__ S,
                                               const int* __restrict__ bsum,
                                               int n, int e2,
                                               float2* __restrict__ csrF,
                                               float* __restrict__ dinv,
                                               int* __restrict__ rowptr, int nbkt) {
    __shared__ int   cnt[256];
    __shared__ float wsm[256];
    __shared__ int   off[256];
    __shared__ float dvs[256];
    __shared__ int   curs[256];
    int b = blockIdx.x, t = threadIdx.x;
    cnt[t] = 0; wsm[t] = 0.f;
    __syncthreads();
    int i0 = b * NB;
    int base = S[i0] + bsum[i0 >> 10];
    int end;
    if (b + 1 < nbkt) { int i1 = (b + 1) * NB; end = S[i1] + bsum[i1 >> 10]; }
    else end = e2;
    for (int i = base + t; i < end; i += 256) {
        uint2 r = csrR[i];
        int d = r.x & 255;
        atomicAdd(&cnt[d], 1);
        atomicAdd(&wsm[d], __uint_as_float(r.y));
    }
    __syncthreads();
    int   myc = cnt[t];
    float w   = wsm[t];
    float dv  = (w > 0.f) ? rsqrtf(w) : 0.f;
    dvs[t] = dv;
    off[t] = myc;
    __syncthreads();
    for (int o = 1; o < 256; o <<= 1) {
        int v = (t >= o) ? off[t - o] : 0;
        __syncthreads();
        off[t] += v;
        __syncthreads();
    }
    int excl = off[t] - myc;
    int node = b * 256 + t;
    if (node < n) { dinv[node] = dv; rowptr[node] = base + excl; }
    if (b == nbkt - 1 && t == 0) rowptr[n] = e2;
    curs[t] = excl;
    __syncthreads();
    for (int i = base + t; i < end; i += 256) {
        uint2 r = csrR[i];
        int d = r.x & 255;
        int src = (int)(r.x >> 8);
        int p = base + atomicAdd(&curs[d], 1);
        csrF[p] = make_float2(__int_as_float(src), __uint_as_float(r.y) * dvs[d]);
    }
}

// ---- MFMA GEMM (layer 1): O[r] = bf16((x@W1)[r] * dinv[r]) ----
__global__ __launch_bounds__(256) void k_gemm_mfma(const float* __restrict__ H,
                                                   const unsigned short* __restrict__ WT,
                                                   const float* __restrict__ dinv,
                                                   unsigned short* __restrict__ O, int n) {
    int wv = threadIdx.x >> 6, lane = threadIdx.x & 63;
    int rowBase = blockIdx.x * 64 + wv * 16;
    int lr = lane & 15;
    int lk = (lane >> 4) * 8;

    int arow = min(rowBase + lr, n - 1);
    bf16x8 a[4];
#pragma unroll
    for (int kk = 0; kk < 4; ++kk) {
        const float4* p = (const float4*)&H[(size_t)arow * 128 + kk * 32 + lk];
        float4 h0 = p[0], h1 = p[1];
        bf16x8 av;
        av[0] = (short)f2bf(h0.x); av[1] = (short)f2bf(h0.y);
        av[2] = (short)f2bf(h0.z); av[3] = (short)f2bf(h0.w);
        av[4] = (short)f2bf(h1.x); av[5] = (short)f2bf(h1.y);
        av[6] = (short)f2bf(h1.z); av[7] = (short)f2bf(h1.w);
        a[kk] = av;
    }

    f32x4 acc[8] = {};
#pragma unroll
    for (int c = 0; c < 8; ++c) {
#pragma unroll
        for (int kk = 0; kk < 4; ++kk) {
            bf16x8 b = *(const bf16x8*)&WT[(size_t)(c * 16 + lr) * 128 + kk * 32 + lk];
            acc[c] = __builtin_amdgcn_mfma_f32_16x16x32_bf16(a[kk], b, acc[c], 0, 0, 0);
        }
    }

#pragma unroll
    for (int r = 0; r < 4; ++r) {
        int node = rowBase + (lane >> 4) * 4 + r;
        if (node < n) {
            float sc = dinv[node];
#pragma unroll
            for (int c = 0; c < 8; ++c)
                O[(size_t)node * 128 + c * 16 + lr] = f2bf(acc[c][r] * sc);
        }
    }
}

// ---- shared agg phase macro body (16 lanes/node, 4 nodes/wave, fp32 accum) ----
#define AGG_BODY(BIAS)                                                          \
    int t = threadIdx.x;                                                        \
    int wv = t >> 6, lane = t & 63;                                             \
    int g = lane >> 4, sl = lane & 15;                                          \
    int node = blockIdx.x * 16 + wv * 4 + g;                                    \
    int s = 0, e = 0;                                                           \
    if (node < n) { s = rowptr[node]; e = rowptr[node + 1]; }                   \
    float a0 = 0.f, a1 = 0.f, a2 = 0.f, a3 = 0.f,                               \
          a4 = 0.f, a5 = 0.f, a6 = 0.f, a7 = 0.f;                               \
    int i = s;                                                                  \
    for (; i + 2 <= e; i += 2) {                                                \
        float2 p0 = csr[i], p1 = csr[i + 1];                                    \
        uint4 v0 = Hw[(size_t)__float_as_int(p0.x) * 16 + sl];                  \
        uint4 v1 = Hw[(size_t)__float_as_int(p1.x) * 16 + sl];                  \
        FMA8(v0, p0.y); FMA8(v1, p1.y);                                         \
    }                                                                           \
    if (i < e) {                                                                \
        float2 pp = csr[i];                                                     \
        uint4 v = Hw[(size_t)__float_as_int(pp.x) * 16 + sl];                   \
        FMA8(v, pp.y);                                                          \
    }                                                                           \
    const float4* b4 = (const float4*)&(BIAS)[sl * 8];                          \
    float4 bb0 = b4[0], bb1 = b4[1];                                            \
    a0 = fmaxf(a0 + bb0.x, 0.f); a1 = fmaxf(a1 + bb0.y, 0.f);                   \
    a2 = fmaxf(a2 + bb0.z, 0.f); a3 = fmaxf(a3 + bb0.w, 0.f);                   \
    a4 = fmaxf(a4 + bb1.x, 0.f); a5 = fmaxf(a5 + bb1.y, 0.f);                   \
    a6 = fmaxf(a6 + bb1.z, 0.f); a7 = fmaxf(a7 + bb1.w, 0.f);                   \
    ushort8 o;                                                                  \
    o[0] = f2bf(a0); o[1] = f2bf(a1); o[2] = f2bf(a2); o[3] = f2bf(a3);         \
    o[4] = f2bf(a4); o[5] = f2bf(a5); o[6] = f2bf(a6); o[7] = f2bf(a7);         \
    *(ushort8*)&lds[wv * 4 + g][sl * 8] = o;                                    \
    __syncthreads();

#define FMA8(V, W8) do {                                              \
    float _w = (W8);                                                  \
    a0 += __uint_as_float((V).x << 16) * _w;                          \
    a1 += __uint_as_float((V).x & 0xFFFF0000u) * _w;                  \
    a2 += __uint_as_float((V).y << 16) * _w;                          \
    a3 += __uint_as_float((V).y & 0xFFFF0000u) * _w;                  \
    a4 += __uint_as_float((V).z << 16) * _w;                          \
    a5 += __uint_as_float((V).z & 0xFFFF0000u) * _w;                  \
    a6 += __uint_as_float((V).w << 16) * _w;                          \
    a7 += __uint_as_float((V).w & 0xFFFF0000u) * _w;                  \
} while (0)

// ---- fused agg1(+b1+relu) -> LDS -> @WT2 * dinv -> bf16 m2 (16-node block, 4.2KB LDS) ----
__global__ __launch_bounds__(256) void k_agg_gemm(const uint4* __restrict__ Hw,
                                                  const int* __restrict__ rowptr,
                                                  const float2* __restrict__ csr,
                                                  const float* __restrict__ bias,
                                                  const unsigned short* __restrict__ WT,
                                                  const float* __restrict__ dinv,
                                                  unsigned short* __restrict__ O, int n) {
    __shared__ __align__(16) unsigned short lds[16][132];
    AGG_BODY(bias)
    // GEMM phase: wave wv computes column-tiles {2wv, 2wv+1} of the 16x128 output
    int lr = lane & 15;
    int lk = (lane >> 4) * 8;
    bf16x8 a[4];
#pragma unroll
    for (int kk = 0; kk < 4; ++kk)
        a[kk] = *(const bf16x8*)&lds[lr][kk * 32 + lk];
    f32x4 acc[2] = {};
#pragma unroll
    for (int c2 = 0; c2 < 2; ++c2) {
        int c = wv * 2 + c2;
#pragma unroll
        for (int kk = 0; kk < 4; ++kk) {
            bf16x8 b = *(const bf16x8*)&WT[(size_t)(c * 16 + lr) * 128 + kk * 32 + lk];
            acc[c2] = __builtin_amdgcn_mfma_f32_16x16x32_bf16(a[kk], b, acc[c2], 0, 0, 0);
        }
    }
#pragma unroll
    for (int r = 0; r < 4; ++r) {
        int n2 = blockIdx.x * 16 + (lane >> 4) * 4 + r;
        if (n2 < n) {
            float sc = dinv[n2];
            O[(size_t)n2 * 128 + (wv * 2 + 0) * 16 + lr] = f2bf(acc[0][r] * sc);
            O[(size_t)n2 * 128 + (wv * 2 + 1) * 16 + lr] = f2bf(acc[1][r] * sc);
        }
    }
}

// ---- fused agg2(+b2+relu) -> LDS -> @WLT * dinv -> fp32 P[n][16] (wave 0 does the 16-wide tile) ----
__global__ __launch_bounds__(256) void k_agg_gemmP(const uint4* __restrict__ Hw,
                                                   const int* __restrict__ rowptr,
                                                   const float2* __restrict__ csr,
                                                   const float* __restrict__ bias,
                                                   const unsigned short* __restrict__ WLT,
                                                   const float* __restrict__ dinv,
                                                   float* __restrict__ P, int n) {
    __shared__ __align__(16) unsigned short lds[16][132];
    AGG_BODY(bias)
    if (wv == 0) {
        int lr = lane & 15;
        int lk = (lane >> 4) * 8;
        f32x4 acc = {};
#pragma unroll
        for (int kk = 0; kk < 4; ++kk) {
            bf16x8 a = *(const bf16x8*)&lds[lr][kk * 32 + lk];
            bf16x8 b = *(const bf16x8*)&WLT[(size_t)lr * 128 + kk * 32 + lk];
            acc = __builtin_amdgcn_mfma_f32_16x16x32_bf16(a, b, acc, 0, 0, 0);
        }
#pragma unroll
        for (int r = 0; r < 4; ++r) {
            int n2 = blockIdx.x * 16 + (lane >> 4) * 4 + r;
            if (n2 < n) P[(size_t)n2 * 16 + lr] = acc[r] * dinv[n2];
        }
    }
}
#undef FMA8
#undef AGG_BODY

// ---------------- fused layer-3 agg + pool (linear path): per-graph edge-sum of P ----------------
__device__ __forceinline__ int lower_bound_i(const int* a, int n, int key) {
    int lo = 0, hi = n;
    while (lo < hi) { int mid = (lo + hi) >> 1; if (a[mid] < key) lo = mid + 1; else hi = mid; }
    return lo;
}

// PB blocks per graph; each walks a contiguous edge subrange (batch sorted => graph edges contiguous)
__global__ __launch_bounds__(256) void k_agg_pool(const float4* __restrict__ P4,
                                                  const int* __restrict__ rowptr,
                                                  const float2* __restrict__ csr,
                                                  const int* __restrict__ batch,
                                                  int n, float* __restrict__ partial) {
    int g = blockIdx.x >> 2, part = blockIdx.x & (PB - 1);
    int start = lower_bound_i(batch, n, g);
    int end   = lower_bound_i(batch, n, g + 1);
    int cn = end - start;
    int ns = start + (cn * part) / PB;
    int ne = start + (cn * (part + 1)) / PB;
    int es = rowptr[ns], ee = rowptr[ne];
    int t = threadIdx.x, grp = t >> 2, sl4 = t & 3;   // 64 groups x 4 lanes
    float a0 = 0.f, a1 = 0.f, a2 = 0.f, a3 = 0.f;
    int i = es + grp;
    for (; i + 64 < ee; i += 128) {
        float2 p0 = csr[i], p1 = csr[i + 64];
        float4 v0 = P4[(size_t)__float_as_int(p0.x) * 4 + sl4];
        float4 v1 = P4[(size_t)__float_as_int(p1.x) * 4 + sl4];
        a0 += v0.x * p0.y; a1 += v0.y * p0.y; a2 += v0.z * p0.y; a3 += v0.w * p0.y;
        a0 += v1.x * p1.y; a1 += v1.y * p1.y; a2 += v1.z * p1.y; a3 += v1.w * p1.y;
    }
    if (i < ee) {
        float2 pp = csr[i];
        float4 v = P4[(size_t)__float_as_int(pp.x) * 4 + sl4];
        a0 += v.x * pp.y; a1 += v.y * pp.y; a2 += v.z * pp.y; a3 += v.w * pp.y;
    }
    __shared__ float red[64][20];
    *(float4*)&red[grp][sl4 * 4] = make_float4(a0, a1, a2, a3);
    __syncthreads();
    if (t < 16) {
        float s = 0.f;
        for (int k2 = 0; k2 < 64; ++k2) s += red[k2][t];
        partial[(size_t)blockIdx.x * 16 + t] = s;
    }
}

// final: reduce PB partials, /cnt, + b3@Wlin + blin
__global__ void k_poolfin(const float* __restrict__ partial, const int* __restrict__ batch,
                          const float* __restrict__ b3, const float* __restrict__ Wlin,
                          const float* __restrict__ blin, float* __restrict__ out, int n) {
    int g = blockIdx.x, t = threadIdx.x;
    if (t >= 16) return;
    int start = lower_bound_i(batch, n, g);
    int end   = lower_bound_i(batch, n, g + 1);
    int cn = end - start;
    float s = partial[(size_t)(g * PB + 0) * 16 + t] + partial[(size_t)(g * PB + 1) * 16 + t]
            + partial[(size_t)(g * PB + 2) * 16 + t] + partial[(size_t)(g * PB + 3) * 16 + t];
    float bw = 0.f;
    for (int ch = 0; ch < 128; ++ch) bw += b3[ch] * Wlin[ch * 16 + t];
    out[g * 16 + t] = (cn > 0) ? s / (float)cn + bw + blin[t] : blin[t];
}

// ---------------- host ----------------
extern "C" void kernel_launch(void* const* d_in, const int* in_sizes, int n_in,
                              void* d_out, int out_size, void* d_ws, size_t ws_size,
                              hipStream_t stream) {
    const float* x    = (const float*)d_in[0];
    const int*   ei   = (const int*)d_in[1];
    const float* ew   = (const float*)d_in[2];
    const int*   batch= (const int*)d_in[3];
    const float* W1   = (const float*)d_in[4];
    const float* b1   = (const float*)d_in[5];
    const float* W2   = (const float*)d_in[6];
    const float* b2   = (const float*)d_in[7];
    const float* W3   = (const float*)d_in[8];
    const float* b3   = (const float*)d_in[9];
    const float* Wlin = (const float*)d_in[10];
    const float* blin = (const float*)d_in[11];
    float* out = (float*)d_out;

    int n  = in_sizes[0] / 128;
    int E  = in_sizes[2];
    int e2 = E + n;
    int G  = out_size / 16;
    const int* row = ei;
    const int* col = ei + E;

    int nbkt = (n + 255) >> 8;          // 256 nodes per bucket
    int M    = nbkt * NB;

    char* ws = (char*)d_ws;
    size_t off = 0;
    auto alloc = [&](size_t bytes) -> void* {
        void* p = ws + off;
        off = (off + bytes + 255) & ~255UL;
        return p;
    };
    // regionA: csrR (e2*8B) during pre; bf16 m2 (n*256B) after k_build
    size_t rawBytes = (size_t)e2 * 8;
    size_t hBytes   = (size_t)n * 128 * 2;
    void* regionA = alloc(rawBytes > hBytes ? rawBytes : hBytes);
    uint2*  csrR  = (uint2*)regionA;
    unsigned short* bufM2 = (unsigned short*)regionA;       // aliases csrR after k_build
    unsigned short* bufM1 = (unsigned short*)alloc((size_t)n * 128 * 2);
    float2* csrF  = (float2*)alloc((size_t)e2 * 8);
    int*    cntA  = (int*)  alloc((size_t)M * 4);
    int*    S     = (int*)  alloc((size_t)M * 4);
    int*    bsum  = (int*)  alloc(4096);
    float*  dinv  = (float*)alloc((size_t)n * 4);
    int*    rowptr= (int*)  alloc((size_t)(n + 1) * 4);
    unsigned short* WT1 = (unsigned short*)alloc(128 * 128 * 2);
    unsigned short* WT2 = (unsigned short*)alloc(128 * 128 * 2);
    unsigned short* WLT = (unsigned short*)alloc(16 * 128 * 2);
    float*  P       = (float*)alloc((size_t)n * 16 * 4);
    float*  partial = (float*)alloc((size_t)G * PB * 16 * 4);
    (void)ws_size;

    int per = (e2 + NB - 1) / NB;
    int nbScan = (M + SCAN_E - 1) / SCAN_E;   // <= 256 for n <= 131072

    // fused weight prep + dst histogram (all independent)
    k_wt3_hist<<<136 + NB, 256, 0, stream>>>(W1, W2, W3, Wlin, WT1, WT2, WLT,
                                             col, E, e2, per, cntA, nbkt);
    k_scan_a<<<nbScan, SCAN_T, 0, stream>>>(cntA, M, S, bsum);
    k_scan_b<<<1, 256, 0, stream>>>(bsum, nbScan);
    k_scatter1<<<NB, 256, 0, stream>>>(row, col, ew, E, e2, per, S, bsum, csrR, nbkt);
    k_build<<<nbkt, 256, 0, stream>>>(csrR, S, bsum, n, e2, csrF, dinv, rowptr, nbkt);

    int gb = (n + 63) / 64;
    int ab = (n + 15) / 16;
    k_gemm_mfma<<<gb, 256, 0, stream>>>(x, WT1, dinv, bufM1, n);
    k_agg_gemm<<<ab, 256, 0, stream>>>((const uint4*)bufM1, rowptr, csrF, b1, WT2, dinv, bufM2, n);
    k_agg_gemmP<<<ab, 256, 0, stream>>>((const uint4*)bufM2, rowptr, csrF, b2, WLT, dinv, P, n);
    k_agg_pool<<<G * PB, 256, 0, stream>>>((const float4*)P, rowptr, csrF, batch, n, partial);
    k_poolfin<<<G, 64, 0, stream>>>(partial, batch, b3, Wlin, blin, out, n);
}